// Round 15
// baseline (575.950 us; speedup 1.0000x reference)
//
#include <hip/hip_runtime.h>
#include <hip/hip_bf16.h>
#include <math.h>

// ---------------------------------------------------------------------------
// Seq2Seq: enc GRU (T=50) + tag GRU (T=20) -> proj -> dec GRU (T=40)
//          -> logits GEMM (1280x50003, K=256, bf16 MFMA) -> LSE -> NLL loss
//
// Round 15: producer-consumer fusion of dec scan + logits (retry of r10 with
// both failure modes fixed):
//  * riders quad-major (5 quads of 256 M-rows x 782 n-tiles): B read once
//    per quad, B-tile loaded BEFORE the spin (dec-independent).
//  * progress flags replicated over 64 cache lines; riders poll their own
//    line; producer publishes every 8 steps (vmcnt(0)+fence+release).
//  * dec blocks 0,1 = r14 dec scan + in-LDS proj; separate k_logits removed.
// Rest identical to r14 (424us): free-rider enc launch, r11 scans.
// ---------------------------------------------------------------------------

#define H 256
#define H3 768
#define NBATCH 32
#define TIN 50
#define TTGT 40
#define TTAG 20
#define VSZ 50003
#define VP 50048          // padded to 64
#define NT 782            // VP / 64
#define MT 1280           // TTGT * NBATCH
#define NGIET 210         // (50+20) timesteps * 3 gates
#define NCVT2 504         // outW cvt worker blocks

typedef float f32x4 __attribute__((ext_vector_type(4)));
typedef short short8 __attribute__((ext_vector_type(8)));

__device__ __forceinline__ float dot4(float4 a, float4 b) {
    return a.x * b.x + a.y * b.y + a.z * b.z + a.w * b.w;
}

__device__ __forceinline__ float bf2f(short s) {
    unsigned int u = ((unsigned int)(unsigned short)s) << 16;
    return __builtin_bit_cast(float, u);
}

__device__ __forceinline__ void bar_lgkm() {
    asm volatile("s_waitcnt lgkmcnt(0)" ::: "memory");
    __builtin_amdgcn_s_barrier();
    __builtin_amdgcn_sched_barrier(0);
}

// ---------------- prep: 3x Wih transpose + zero progress flags -------------
__global__ void k_prep(const float* eWih, const float* tWih, const float* dWih,
                       float* d0, float* d1, float* d2, int* progrep) {
    int which = blockIdx.y;
    if (which == 0 && blockIdx.x == 0) {
        for (int i = threadIdx.x; i < 1024; i += 256) progrep[i] = 0;
    }
    const float* s = which == 0 ? eWih : (which == 1 ? tWih : dWih);
    float* d = which == 0 ? d0 : (which == 1 ? d1 : d2);
    int n = blockIdx.x;
    for (int k = threadIdx.x; k < H; k += 256)
        d[(size_t)(k >> 2) * (H3 * 4) + n * 4 + (k & 3)] = s[(size_t)n * H + k];
}

// ---------------- gi(enc,tag) + Whh->frags + proj transpose ----------------
__global__ __launch_bounds__(256) void k_gi_prep(
    const int* in_toks, const int* tag_toks, const float* enc_emb,
    const float* tag_emb, const float* W4e, const float* W4t,
    const float* bih_e, const float* bhh_e, const float* bih_t,
    const float* bhh_t, __hip_bfloat16* gi_e, __hip_bfloat16* gi_t,
    const float* eWhh, const float* tWhh, const float* dWhh,
    __hip_bfloat16* p0, __hip_bfloat16* p1, __hip_bfloat16* p2,
    const float* projW, float* W4_proj) {
    int bx = blockIdx.x, tid = threadIdx.x;
    if (bx >= 498) {
        int n = bx - 498;
        for (int k = tid; k < 2 * H; k += 256)
            W4_proj[(size_t)(k >> 2) * 1024 + n * 4 + (k & 3)] =
                projW[(size_t)n * 2 * H + k];
        return;
    }
    if (bx >= NGIET) {
        int wb = bx - NGIET;
        int m = wb / 96;
        const float* s = m == 0 ? eWhh : (m == 1 ? tWhh : dWhh);
        __hip_bfloat16* d = m == 0 ? p0 : (m == 1 ? p1 : p2);
        int idx = (wb % 96) * 256 + tid;
        int lane = idx & 63;
        int f = (idx >> 6) % 24;
        int w = idx / (24 * 64);
        int ks = f / 3, q = f % 3;
        int row = (q << 8) + (w << 4) + (lane & 15);
        int k = (ks << 5) + ((lane >> 4) << 3);
#pragma unroll
        for (int j = 0; j < 8; ++j)
            d[(size_t)idx * 8 + j] = __float2bfloat16(s[(size_t)row * H + k + j]);
        return;
    }
    __shared__ float x[NBATCH][H];
    int g = bx % 3, tt = bx / 3;
    const int* toks;
    const float* emb;
    const float* W4;
    const float* bihp;
    const float* bhhp;
    __hip_bfloat16* gip;
    int t;
    if (tt < TIN) {
        toks = in_toks; emb = enc_emb; W4 = W4e; bihp = bih_e; bhhp = bhh_e;
        gip = gi_e; t = tt;
    } else {
        toks = tag_toks; emb = tag_emb; W4 = W4t; bihp = bih_t; bhhp = bhh_t;
        gip = gi_t; t = tt - TIN;
    }
    for (int b = 0; b < NBATCH; ++b)
        x[b][tid] = emb[(size_t)toks[t * NBATCH + b] * H + tid];
    __syncthreads();
    int nb_ = tid & 63, mg = tid >> 6;
    float acc[4][8];
#pragma unroll
    for (int j = 0; j < 4; ++j)
#pragma unroll
        for (int mi = 0; mi < 8; ++mi) acc[j][mi] = 0.f;
    for (int k4 = 0; k4 < 64; ++k4) {
        const float4* wrow = (const float4*)(W4 + (size_t)k4 * 3072);
        float4 w0 = wrow[g * 256 + nb_];
        float4 w1 = wrow[g * 256 + nb_ + 64];
        float4 w2 = wrow[g * 256 + nb_ + 128];
        float4 w3 = wrow[g * 256 + nb_ + 192];
#pragma unroll
        for (int mi = 0; mi < 8; ++mi) {
            float4 xv = *(const float4*)&x[mg * 8 + mi][k4 * 4];
            acc[0][mi] += dot4(xv, w0);
            acc[1][mi] += dot4(xv, w1);
            acc[2][mi] += dot4(xv, w2);
            acc[3][mi] += dot4(xv, w3);
        }
    }
#pragma unroll
    for (int j = 0; j < 4; ++j) {
        int n = g * 256 + nb_ + j * 64;
        float bv = bihp[n] + (g < 2 ? bhhp[n] : 0.0f);
        int nn = n & 255;
        int ww = nn >> 4, lrr = nn & 15;
#pragma unroll
        for (int mi = 0; mi < 8; ++mi) {
            int bm = mg * 8 + mi;
            int locb = bm >> 4, lmm = bm & 15;
            int lgg = lmm >> 2, reg = lmm & 3;
            size_t idx = ((size_t)(t * 2 + locb) * 16 + ww) * 1024 +
                         reg * 256 + (lgg * 16 + lrr) * 4 + g;
            gip[idx] = __float2bfloat16(acc[j][mi] + bv);
        }
    }
}

// ---------------- enc+tag scan + free-riding gi_dec / outW-cvt blocks ------
__global__ __launch_bounds__(1024) void k_scan_enc(
    const __hip_bfloat16* gi1, const __hip_bfloat16* W1, const float* bhh1,
    float* hT1, int T1,
    const __hip_bfloat16* gi2, const __hip_bfloat16* W2, const float* bhh2,
    float* hT2, int T2,
    const int* tgt_toks, const float* enc_emb, const float* W4d,
    const float* bih_d, const float* bhh_d, __hip_bfloat16* gi_d,
    const float* outW, __hip_bfloat16* outWb) {
    __shared__ uint4 WL[16 * 6 * 64];  // 96KB
    __shared__ uint4 HBF[2][512];      // 16KB

    int blk = blockIdx.x, tid = threadIdx.x;
    if (blk >= 4) {
        int wb = blk - 4;
        if (wb < TTGT) {
            int t = wb;
            float* x = (float*)WL;
            if (tid < 256) {
                for (int b = 0; b < NBATCH; ++b) {
                    int tok = (t == 0) ? 1 : tgt_toks[(t - 1) * NBATCH + b];
                    x[b * 256 + tid] = fmaxf(enc_emb[(size_t)tok * H + tid], 0.0f);
                }
            }
            __syncthreads();
            if (tid < 768) {
                int g = tid >> 8, tidg = tid & 255;
                int nb_ = tidg & 63, mg = tidg >> 6;
                float acc[4][8];
#pragma unroll
                for (int j = 0; j < 4; ++j)
#pragma unroll
                    for (int mi = 0; mi < 8; ++mi) acc[j][mi] = 0.f;
                for (int k4 = 0; k4 < 64; ++k4) {
                    const float4* wrow = (const float4*)(W4d + (size_t)k4 * 3072);
                    float4 w0 = wrow[g * 256 + nb_];
                    float4 w1 = wrow[g * 256 + nb_ + 64];
                    float4 w2 = wrow[g * 256 + nb_ + 128];
                    float4 w3 = wrow[g * 256 + nb_ + 192];
#pragma unroll
                    for (int mi = 0; mi < 8; ++mi) {
                        float4 xv = *(const float4*)&x[(mg * 8 + mi) * 256 + k4 * 4];
                        acc[0][mi] += dot4(xv, w0);
                        acc[1][mi] += dot4(xv, w1);
                        acc[2][mi] += dot4(xv, w2);
                        acc[3][mi] += dot4(xv, w3);
                    }
                }
#pragma unroll
                for (int j = 0; j < 4; ++j) {
                    int n = g * 256 + nb_ + j * 64;
                    float bv = bih_d[n] + (g < 2 ? bhh_d[n] : 0.0f);
                    int nn = n & 255;
                    int ww = nn >> 4, lrr = nn & 15;
#pragma unroll
                    for (int mi = 0; mi < 8; ++mi) {
                        int bm = mg * 8 + mi;
                        int locb = bm >> 4, lmm = bm & 15;
                        int lgg = lmm >> 2, reg = lmm & 3;
                        size_t idx = ((size_t)(t * 2 + locb) * 16 + ww) * 1024 +
                                     reg * 256 + (lgg * 16 + lrr) * 4 + g;
                        gi_d[idx] = __float2bfloat16(acc[j][mi] + bv);
                    }
                }
            }
            return;
        }
        const size_t total = (size_t)VP * H / 4;
        const size_t stride = (size_t)NCVT2 * 1024;
        for (size_t i = (size_t)(wb - TTGT) * 1024 + tid; i < total; i += stride) {
            size_t i4 = i * 4;
            int row = (int)(i4 >> 8);
            float4 v;
            if (row < VSZ) v = *(const float4*)(outW + i4);
            else v = make_float4(0.f, 0.f, 0.f, 0.f);
            outWb[i4 + 0] = __float2bfloat16(v.x);
            outWb[i4 + 1] = __float2bfloat16(v.y);
            outWb[i4 + 2] = __float2bfloat16(v.z);
            outWb[i4 + 3] = __float2bfloat16(v.w);
        }
        return;
    }

    const __hip_bfloat16 *gip, *Wg;
    const float* bhh;
    float* hTp;
    int T, loc;
    if (blk < 2) {
        gip = gi1; Wg = W1; bhh = bhh1; hTp = hT1; T = T1; loc = blk;
    } else {
        gip = gi2; Wg = W2; bhh = bhh2; hTp = hT2; T = T2; loc = blk - 2;
    }
    int mb = loc * 16;
    int w = tid >> 6, lane = tid & 63, lr = lane & 15, lg = lane >> 4;

    short8 wreg[18];
    const uint4* Wg4 = (const uint4*)Wg;
#pragma unroll
    for (int f = 0; f < 18; ++f) {
        uint4 v = Wg4[(size_t)(w * 24 + f) * 64 + lane];
        wreg[f] = *(short8*)&v;
    }
#pragma unroll
    for (int i = 0; i < 6; ++i)
        WL[(w * 6 + i) * 64 + lane] = Wg4[(size_t)(w * 24 + 18 + i) * 64 + lane];

    float bnv = bhh[512 + w * 16 + lr];

    float hprev[4];
    short* HB16 = (short*)HBF;
#pragma unroll
    for (int reg = 0; reg < 4; ++reg) {
        int row = lg * 4 + reg;
        hprev[reg] = 0.0f;
        int ch = w * 2 + (lr >> 3);
        int slot = ch ^ (row & 7);
        HB16[row * 256 + slot * 8 + (lr & 7)] = 0;
    }
    uint2 gv[4];
    {
        const __hip_bfloat16* gp = gip + ((size_t)loc * 16 + w) * 1024;
#pragma unroll
        for (int reg = 0; reg < 4; ++reg)
            gv[reg] = *(const uint2*)(gp + reg * 256 + lane * 4);
    }
    __syncthreads();

    const short8* HSbase = (const short8*)HBF;
    const short8* WLs = (const short8*)WL;
    for (int t = 0; t < T; ++t) {
        int p = t & 1, p2 = p ^ 1;
        const short8* HS = HSbase + p * 512;
        f32x4 acc[3];
        acc[0] = (f32x4){0.f, 0.f, 0.f, 0.f};
        acc[1] = acc[0];
        acc[2] = (f32x4){bnv, bnv, bnv, bnv};
#pragma unroll
        for (int ks = 0; ks < 6; ++ks) {
            short8 a = HS[lr * 32 + ((ks * 4 + lg) ^ (lr & 7))];
#pragma unroll
            for (int q = 0; q < 3; ++q)
                acc[q] = __builtin_amdgcn_mfma_f32_16x16x32_bf16(
                    a, wreg[ks * 3 + q], acc[q], 0, 0, 0);
        }
#pragma unroll
        for (int ks = 6; ks < 8; ++ks) {
            short8 a = HS[lr * 32 + ((ks * 4 + lg) ^ (lr & 7))];
#pragma unroll
            for (int q = 0; q < 3; ++q) {
                short8 bv = WLs[(w * 6 + (ks - 6) * 3 + q) * 64 + lane];
                acc[q] = __builtin_amdgcn_mfma_f32_16x16x32_bf16(
                    a, bv, acc[q], 0, 0, 0);
            }
        }
#pragma unroll
        for (int reg = 0; reg < 4; ++reg) {
            uint2 u = gv[reg];
            float gr = bf2f((short)(u.x & 0xffff));
            float gz = bf2f((short)(u.x >> 16));
            float gn = bf2f((short)(u.y & 0xffff));
            float er = __expf(-(gr + acc[0][reg]));
            float r = __builtin_amdgcn_rcpf(1.0f + er);
            float ez = __expf(-(gz + acc[1][reg]));
            float z = __builtin_amdgcn_rcpf(1.0f + ez);
            float xx = gn + r * acc[2][reg];
            float e2 = __expf(-2.0f * fabsf(xx));
            float nv = copysignf((1.0f - e2) * __builtin_amdgcn_rcpf(1.0f + e2), xx);
            float hnew = (1.0f - z) * nv + z * hprev[reg];
            hprev[reg] = hnew;
            __hip_bfloat16 qb = __float2bfloat16(hnew);
            int row = lg * 4 + reg;
            int ch = w * 2 + (lr >> 3);
            int slot = ch ^ (row & 7);
            HB16[p2 * 4096 + row * 256 + slot * 8 + (lr & 7)] = *(short*)&qb;
        }
        if (t + 1 < T) {
            const __hip_bfloat16* gp =
                gip + ((size_t)((t + 1) * 2 + loc) * 16 + w) * 1024;
#pragma unroll
            for (int reg = 0; reg < 4; ++reg)
                gv[reg] = *(const uint2*)(gp + reg * 256 + lane * 4);
        }
        bar_lgkm();
    }
    if (hTp) {
#pragma unroll
        for (int reg = 0; reg < 4; ++reg) {
            int row = lg * 4 + reg, col = w * 16 + lr;
            hTp[(size_t)(mb + row) * H + col] = hprev[reg];
        }
    }
}

// ---------------- fused dec scan (+proj) + logits riders -------------------
// blocks 0,1: dec scan, publishes progress (replicated over 64 cache lines).
// blocks 2+: logits, quad-major (5 quads x 782 n-tiles), 16 waves = 4 M-tiles.
__global__ __launch_bounds__(1024) void k_declog(
    const __hip_bfloat16* gip, const __hip_bfloat16* Wg, const float* bhh,
    __hip_bfloat16* decA, int* progrep,
    const float* tagh, const float* ench, const float* W4p, const float* pb,
    const __hip_bfloat16* Bw, const float* bias, float* dout,
    float* pmax, float* psum) {
    __shared__ __align__(16) char smem[114688];
    int tid = threadIdx.x;
    int wave = tid >> 6, lane = tid & 63, lr = lane & 15, lg = lane >> 4;

    if (blockIdx.x >= 2) {
        // ================= logits rider =================
        uint4* bsm = (uint4*)smem;               // 32KB B tile
        float* cst = (float*)(smem + 32768);     // [16][16][68] staging
        int lb = blockIdx.x - 2;
        int quad = lb / NT, nblk = lb % NT;
        int wq = wave >> 2, wsub = wave & 3;
        int m0 = quad * 256 + wq * 64;
        int n0 = nblk * 64;
        const uint4* Bg = (const uint4*)(Bw + (size_t)n0 * H);
#pragma unroll
        for (int i = 0; i < 2; ++i) {
            int c = tid + i * 1024;
            int r = c >> 5, g = c & 31;
            bsm[(r << 5) | (g ^ (r & 7))] = Bg[c];
        }
        float biasv[4];
        bool valid[4];
#pragma unroll
        for (int ns = 0; ns < 4; ++ns) {
            int n = n0 + ns * 16 + lr;
            valid[ns] = (n < VSZ);
            biasv[ns] = valid[ns] ? bias[n] : 0.f;
        }
        if (tid == 0) {
            int need = quad * 8 + 8;
            int line = (blockIdx.x & 63) * 16;
            while (true) {
                int p0 = __hip_atomic_load(&progrep[line + 0], __ATOMIC_ACQUIRE,
                                           __HIP_MEMORY_SCOPE_AGENT);
                int p1 = __hip_atomic_load(&progrep[line + 1], __ATOMIC_ACQUIRE,
                                           __HIP_MEMORY_SCOPE_AGENT);
                if (p0 >= need && p1 >= need) break;
                for (int s = 0; s < 8; ++s) __builtin_amdgcn_s_sleep(64);
            }
        }
        __syncthreads();
        short8 areg[8];
        const uint4* Ar = (const uint4*)(decA + (size_t)(m0 + wsub * 16 + lr) * H);
#pragma unroll
        for (int ks = 0; ks < 8; ++ks) {
            uint4 v = Ar[ks * 4 + lg];
            areg[ks] = *(short8*)&v;
        }
        f32x4 acc[4];
#pragma unroll
        for (int ns = 0; ns < 4; ++ns) acc[ns] = (f32x4){0.f, 0.f, 0.f, 0.f};
        const short8* L = (const short8*)bsm;
#pragma unroll
        for (int ks = 0; ks < 8; ++ks) {
            int ga = ks * 4 + lg;
#pragma unroll
            for (int ns = 0; ns < 4; ++ns) {
                int rb = ns * 16 + lr;
                acc[ns] = __builtin_amdgcn_mfma_f32_16x16x32_bf16(
                    areg[ks], L[(rb << 5) | (ga ^ (rb & 7))], acc[ns], 0, 0, 0);
            }
        }
        float* cw = cst + wave * (16 * 68);
#pragma unroll
        for (int reg = 0; reg < 4; ++reg) {
            int m = m0 + wsub * 16 + lg * 4 + reg;
            float v[4];
            float rm = -INFINITY;
#pragma unroll
            for (int ns = 0; ns < 4; ++ns) {
                v[ns] = acc[ns][reg] + biasv[ns];
                if (valid[ns]) rm = fmaxf(rm, v[ns]);
                cw[(lg * 4 + reg) * 68 + ns * 16 + lr] = v[ns];
            }
            for (int off = 1; off < 16; off <<= 1) rm = fmaxf(rm, __shfl_xor(rm, off));
            float se = 0.f;
#pragma unroll
            for (int ns = 0; ns < 4; ++ns)
                if (valid[ns]) se += __expf(v[ns] - rm);
            for (int off = 1; off < 16; off <<= 1) se += __shfl_xor(se, off);
            if (lr == 0) {
                pmax[(size_t)m * NT + nblk] = rm;
                psum[(size_t)m * NT + nblk] = se;
            }
        }
        float* dbase = dout + 2 + (size_t)(m0 + wsub * 16) * VSZ + n0;
        int c0 = lr * 4;
        bool full = (n0 + c0 + 3 < VSZ);
#pragma unroll
        for (int it = 0; it < 4; ++it) {
            int row = it * 4 + lg;
            f32x4 v4 = *(const f32x4*)&cw[row * 68 + c0];
            float* pp = dbase + (size_t)row * VSZ + c0;
            if (full) {
                __builtin_memcpy(pp, &v4, 16);
            } else {
#pragma unroll
                for (int j = 0; j < 4; ++j)
                    if (n0 + c0 + j < VSZ) pp[j] = v4[j];
            }
        }
        return;
    }

    // ================= dec scan (blocks 0,1) =================
    uint4* WL = (uint4*)smem;                 // 96KB
    uint4* HBF = (uint4*)(smem + 98304);      // 16KB
    int loc = blockIdx.x, mb = loc * 16;
    int w = wave;
    const int T = TTGT;

    // proj in WL space
    float* CC = (float*)WL;
    float* MM = ((float*)WL) + 8192;
#pragma unroll
    for (int i = 0; i < 8; ++i) {
        int idx = i * 1024 + tid;
        int row = idx >> 9, col = idx & 511;
        float v = (col < 256) ? tagh[(size_t)(mb + row) * H + col]
                              : ench[(size_t)(mb + row) * H + (col - 256)];
        CC[idx] = v;
    }
    __syncthreads();
    {
        int col = tid & 255, rg = tid >> 8;
        float a0 = 0.f, a1 = 0.f, a2 = 0.f, a3 = 0.f;
        for (int k4 = 0; k4 < 128; ++k4) {
            float4 wv = ((const float4*)(W4p + (size_t)k4 * 1024))[col];
            float4 c0 = *(const float4*)&CC[(rg * 4 + 0) * 512 + k4 * 4];
            float4 c1 = *(const float4*)&CC[(rg * 4 + 1) * 512 + k4 * 4];
            float4 c2 = *(const float4*)&CC[(rg * 4 + 2) * 512 + k4 * 4];
            float4 c3 = *(const float4*)&CC[(rg * 4 + 3) * 512 + k4 * 4];
            a0 += dot4(c0, wv);
            a1 += dot4(c1, wv);
            a2 += dot4(c2, wv);
            a3 += dot4(c3, wv);
        }
        float bv = pb[col];
        __syncthreads();
        MM[(rg * 4 + 0) * 256 + col] = a0 + bv;
        MM[(rg * 4 + 1) * 256 + col] = a1 + bv;
        MM[(rg * 4 + 2) * 256 + col] = a2 + bv;
        MM[(rg * 4 + 3) * 256 + col] = a3 + bv;
    }
    __syncthreads();

    float hprev[4];
    short* HB16 = (short*)HBF;
#pragma unroll
    for (int reg = 0; reg < 4; ++reg) {
        int row = lg * 4 + reg, col = w * 16 + lr;
        float hv = MM[row * 256 + col];
        hprev[reg] = hv;
        __hip_bfloat16 q = __float2bfloat16(hv);
        int ch = w * 2 + (lr >> 3);
        int slot = ch ^ (row & 7);
        HB16[row * 256 + slot * 8 + (lr & 7)] = *(short*)&q;
    }
    __syncthreads();

    short8 wreg[18];
    const uint4* Wg4 = (const uint4*)Wg;
#pragma unroll
    for (int f = 0; f < 18; ++f) {
        uint4 v = Wg4[(size_t)(w * 24 + f) * 64 + lane];
        wreg[f] = *(short8*)&v;
    }
#pragma unroll
    for (int i = 0; i < 6; ++i)
        WL[(w * 6 + i) * 64 + lane] = Wg4[(size_t)(w * 24 + 18 + i) * 64 + lane];

    float bnv = bhh[512 + w * 16 + lr];

    uint2 gv[4];
    {
        const __hip_bfloat16* gp = gip + ((size_t)loc * 16 + w) * 1024;
#pragma unroll
        for (int reg = 0; reg < 4; ++reg)
            gv[reg] = *(const uint2*)(gp + reg * 256 + lane * 4);
    }
    __syncthreads();

    const short8* HSbase = (const short8*)HBF;
    const short8* WLs = (const short8*)WL;
    for (int t = 0; t < T; ++t) {
        int p = t & 1, p2 = p ^ 1;
        const short8* HS = HSbase + p * 512;
        f32x4 acc[3];
        acc[0] = (f32x4){0.f, 0.f, 0.f, 0.f};
        acc[1] = acc[0];
        acc[2] = (f32x4){bnv, bnv, bnv, bnv};
#pragma unroll
        for (int ks = 0; ks < 6; ++ks) {
            short8 a = HS[lr * 32 + ((ks * 4 + lg) ^ (lr & 7))];
#pragma unroll
            for (int q = 0; q < 3; ++q)
                acc[q] = __builtin_amdgcn_mfma_f32_16x16x32_bf16(
                    a, wreg[ks * 3 + q], acc[q], 0, 0, 0);
        }
#pragma unroll
        for (int ks = 6; ks < 8; ++ks) {
            short8 a = HS[lr * 32 + ((ks * 4 + lg) ^ (lr & 7))];
#pragma unroll
            for (int q = 0; q < 3; ++q) {
                short8 bv = WLs[(w * 6 + (ks - 6) * 3 + q) * 64 + lane];
                acc[q] = __builtin_amdgcn_mfma_f32_16x16x32_bf16(
                    a, bv, acc[q], 0, 0, 0);
            }
        }
#pragma unroll
        for (int reg = 0; reg < 4; ++reg) {
            uint2 u = gv[reg];
            float gr = bf2f((short)(u.x & 0xffff));
            float gz = bf2f((short)(u.x >> 16));
            float gn = bf2f((short)(u.y & 0xffff));
            float er = __expf(-(gr + acc[0][reg]));
            float r = __builtin_amdgcn_rcpf(1.0f + er);
            float ez = __expf(-(gz + acc[1][reg]));
            float z = __builtin_amdgcn_rcpf(1.0f + ez);
            float xx = gn + r * acc[2][reg];
            float e2 = __expf(-2.0f * fabsf(xx));
            float nv = copysignf((1.0f - e2) * __builtin_amdgcn_rcpf(1.0f + e2), xx);
            float hnew = (1.0f - z) * nv + z * hprev[reg];
            hprev[reg] = hnew;
            __hip_bfloat16 qb = __float2bfloat16(hnew);
            int row = lg * 4 + reg;
            int ch = w * 2 + (lr >> 3);
            int slot = ch ^ (row & 7);
            HB16[p2 * 4096 + row * 256 + slot * 8 + (lr & 7)] = *(short*)&qb;
        }
        if (t + 1 < T) {
            const __hip_bfloat16* gp =
                gip + ((size_t)((t + 1) * 2 + loc) * 16 + w) * 1024;
#pragma unroll
            for (int reg = 0; reg < 4; ++reg)
                gv[reg] = *(const uint2*)(gp + reg * 256 + lane * 4);
        }
        if (t >= 1 && tid < 512) {
            int lb2 = tid >> 5, ch2 = tid & 31;
            short8 hv = HSbase[p * 512 + lb2 * 32 + (ch2 ^ (lb2 & 7))];
            *(short8*)(decA + (size_t)((t - 1) * NBATCH + mb + lb2) * H + ch2 * 8) = hv;
        }
        // publish progress: slices 0..t-1 are issued; drain + release
        bool pub = (t >= 8) && ((t & 7) == 0);
        if (pub) asm volatile("s_waitcnt vmcnt(0)" ::: "memory");
        bar_lgkm();
        if (pub && tid == 0) {
            __threadfence();
            for (int i = 0; i < 64; ++i)
                __hip_atomic_store(&progrep[i * 16 + loc], t, __ATOMIC_RELEASE,
                                   __HIP_MEMORY_SCOPE_AGENT);
        }
    }
    if (tid < 512) {
        int lb2 = tid >> 5, ch2 = tid & 31;
        short8 hv = HSbase[(T & 1) * 512 + lb2 * 32 + (ch2 ^ (lb2 & 7))];
        *(short8*)(decA + (size_t)((T - 1) * NBATCH + mb + lb2) * H + ch2 * 8) = hv;
    }
    asm volatile("s_waitcnt vmcnt(0)" ::: "memory");
    __syncthreads();
    if (tid == 0) {
        __threadfence();
        for (int i = 0; i < 64; ++i)
            __hip_atomic_store(&progrep[i * 16 + loc], TTGT, __ATOMIC_RELEASE,
                               __HIP_MEMORY_SCOPE_AGENT);
    }
}

// ---------------- per-row logsumexp from tile partials ---------------------
__global__ void k_lse(const float* pmax, const float* psum, float* lse) {
    int m = blockIdx.x, tid = threadIdx.x;
    __shared__ float sm[4];
    float lm = -INFINITY;
    for (int i = tid; i < NT; i += 256) lm = fmaxf(lm, pmax[(size_t)m * NT + i]);
    for (int off = 1; off < 64; off <<= 1) lm = fmaxf(lm, __shfl_xor(lm, off));
    if ((tid & 63) == 0) sm[tid >> 6] = lm;
    __syncthreads();
    float M = fmaxf(fmaxf(sm[0], sm[1]), fmaxf(sm[2], sm[3]));
    __syncthreads();
    float s = 0.f;
    for (int i = tid; i < NT; i += 256)
        s += psum[(size_t)m * NT + i] * __expf(pmax[(size_t)m * NT + i] - M);
    for (int off = 1; off < 64; off <<= 1) s += __shfl_xor(s, off);
    if ((tid & 63) == 0) sm[tid >> 6] = s;
    __syncthreads();
    if (tid == 0) lse[m] = M + logf(sm[0] + sm[1] + sm[2] + sm[3]);
}

// ---------------- final NLL loss -------------------------------------------
__global__ void k_loss(const float* lse, const int* tgt, float* dout) {
    int tid = threadIdx.x;
    __shared__ float sm[4];
    float s = 0.f;
    for (int m = tid; m < MT; m += 256) {
        int tg = tgt[m];
        s += lse[m] - dout[2 + (size_t)m * VSZ + tg];
    }
    for (int off = 1; off < 64; off <<= 1) s += __shfl_xor(s, off);
    if ((tid & 63) == 0) sm[tid >> 6] = s;
    __syncthreads();
    if (tid == 0) {
        float total = sm[0] + sm[1] + sm[2] + sm[3];
        dout[0] = total / 32.0f;    // sum over t of mean over batch
        dout[1] = total / 1280.0f;  // / T_tgt
    }
}

// ---------------------------------------------------------------------------
extern "C" void kernel_launch(void* const* d_in, const int* in_sizes, int n_in,
                              void* d_out, int out_size, void* d_ws,
                              size_t ws_size, hipStream_t stream) {
    const int* input_tensor = (const int*)d_in[0];
    const int* target_tensor = (const int*)d_in[1];
    const int* tag_tensor = (const int*)d_in[2];
    const float* enc_emb = (const float*)d_in[3];
    const float* enc_Wih = (const float*)d_in[4];
    const float* enc_Whh = (const float*)d_in[5];
    const float* enc_bih = (const float*)d_in[6];
    const float* enc_bhh = (const float*)d_in[7];
    const float* tag_emb = (const float*)d_in[8];
    const float* tag_Wih = (const float*)d_in[9];
    const float* tag_Whh = (const float*)d_in[10];
    const float* tag_bih = (const float*)d_in[11];
    const float* tag_bhh = (const float*)d_in[12];
    const float* proj_W = (const float*)d_in[13];
    const float* proj_b = (const float*)d_in[14];
    const float* dec_Wih = (const float*)d_in[15];
    const float* dec_Whh = (const float*)d_in[16];
    const float* dec_bih = (const float*)d_in[17];
    const float* dec_bhh = (const float*)d_in[18];
    const float* out_W = (const float*)d_in[19];
    const float* out_b = (const float*)d_in[20];

    char* wsb = (char*)d_ws;
    size_t o = 0;
    auto alloc = [&](size_t bytes) {
        size_t r = o;
        o += (bytes + 511) & ~(size_t)511;
        return r;
    };
    float* W4_enc_ih = (float*)(wsb + alloc(H3 * H * 4));
    float* W4_tag_ih = (float*)(wsb + alloc(H3 * H * 4));
    float* W4_dec_ih = (float*)(wsb + alloc(H3 * H * 4));
    float* W4_proj   = (float*)(wsb + alloc(H * 2 * H * 4));
    __hip_bfloat16* gi_enc = (__hip_bfloat16*)(wsb + alloc((size_t)TIN * 65536));
    __hip_bfloat16* gi_tag = (__hip_bfloat16*)(wsb + alloc((size_t)TTAG * 65536));
    __hip_bfloat16* gi_dec = (__hip_bfloat16*)(wsb + alloc((size_t)TTGT * 65536));
    float* enc_h  = (float*)(wsb + alloc(NBATCH * H * 4));
    float* tag_h  = (float*)(wsb + alloc(NBATCH * H * 4));
    float* lse    = (float*)(wsb + alloc(MT * 4));
    int*   progrep = (int*)(wsb + alloc(1024 * 4));
    __hip_bfloat16* Wp_enc = (__hip_bfloat16*)(wsb + alloc(H3 * H * 2));
    __hip_bfloat16* Wp_tag = (__hip_bfloat16*)(wsb + alloc(H3 * H * 2));
    __hip_bfloat16* Wp_dec = (__hip_bfloat16*)(wsb + alloc(H3 * H * 2));
    __hip_bfloat16* outWb  = (__hip_bfloat16*)(wsb + alloc((size_t)VP * H * 2));
    __hip_bfloat16* decA   = (__hip_bfloat16*)(wsb + alloc((size_t)MT * H * 2));
    float* pmax = (float*)(wsb + alloc((size_t)MT * NT * 4));
    float* psum = (float*)(wsb + alloc((size_t)MT * NT * 4));

    float* dout = (float*)d_out;

    // 1) Wih transposes + zero progress flags
    k_prep<<<dim3(H3, 3), 256, 0, stream>>>(enc_Wih, tag_Wih, dec_Wih,
                                            W4_enc_ih, W4_tag_ih, W4_dec_ih,
                                            progrep);

    // 2) gi(enc,tag) + Whh->frags + proj transpose
    k_gi_prep<<<754, 256, 0, stream>>>(
        input_tensor, tag_tensor, enc_emb, tag_emb, W4_enc_ih, W4_tag_ih,
        enc_bih, enc_bhh, tag_bih, tag_bhh, gi_enc, gi_tag,
        enc_Whh, tag_Whh, dec_Whh, Wp_enc, Wp_tag, Wp_dec, proj_W, W4_proj);

    // 3) enc+tag scans + free-riding gi_dec + outW cvt
    k_scan_enc<<<4 + TTGT + NCVT2, 1024, 0, stream>>>(
        gi_enc, Wp_enc, enc_bhh, enc_h, TIN,
        gi_tag, Wp_tag, tag_bhh, tag_h, TTAG,
        target_tensor, enc_emb, W4_dec_ih, dec_bih, dec_bhh, gi_dec,
        out_W, outWb);

    // 4) fused dec scan + logits riders (grid = 2 + 5*782)
    k_declog<<<2 + 5 * NT, 1024, 0, stream>>>(
        gi_dec, Wp_dec, dec_bhh, decA, progrep,
        tag_h, enc_h, W4_proj, proj_b,
        outWb, out_b, dout, pmax, psum);

    // 5) per-row logsumexp
    k_lse<<<MT, 256, 0, stream>>>(pmax, psum, lse);

    // 6) loss scalars
    k_loss<<<1, 256, 0, stream>>>(lse, target_tensor, dout);
}

// Round 16
// 423.496 us; speedup vs baseline: 1.3600x; 1.3600x over previous
//
#include <hip/hip_runtime.h>
#include <hip/hip_bf16.h>
#include <math.h>

// ---------------------------------------------------------------------------
// Seq2Seq: enc GRU (T=50) + tag GRU (T=20) -> proj -> dec GRU (T=40)
//          -> logits GEMM (1280x50003, K=256, bf16 MFMA) -> LSE -> NLL loss
//
// Round 16: REVERT to round-14 (424.5us session best).  Round-15's
// producer-consumer fusion regressed (430us fused kernel: 1 block/CU
// occupancy + rider spin serialization + B refetch).  Fusion abandoned;
// this serial structure is the validated optimum:
//  * k_scan_enc carries 40 gi_dec blocks + 504 outW->bf16 cvt blocks as
//    fully independent extra blocks (no cross-block sync; scan blocks 0-3).
//  * Whh-frag prep + proj transpose in the gi launch.
//  * dec scan does proj in-LDS; k_proj launch removed.
//  * logits 64x64, A->regs, swizzled-LDS B, float4 stores.
// ---------------------------------------------------------------------------

#define H 256
#define H3 768
#define NBATCH 32
#define TIN 50
#define TTGT 40
#define TTAG 20
#define VSZ 50003
#define VP 50048          // padded to 64
#define NT 782            // VP / 64
#define MT 1280           // TTGT * NBATCH
#define NGIET 210         // (50+20) timesteps * 3 gates
#define NCVT2 504         // outW cvt worker blocks (1024 thr, grid-stride)

typedef float f32x4 __attribute__((ext_vector_type(4)));
typedef short short8 __attribute__((ext_vector_type(8)));

__device__ __forceinline__ float dot4(float4 a, float4 b) {
    return a.x * b.x + a.y * b.y + a.z * b.z + a.w * b.w;
}

__device__ __forceinline__ float bf2f(short s) {
    unsigned int u = ((unsigned int)(unsigned short)s) << 16;
    return __builtin_bit_cast(float, u);
}

// barrier with LDS-only drain: leaves global loads in flight
__device__ __forceinline__ void bar_lgkm() {
    asm volatile("s_waitcnt lgkmcnt(0)" ::: "memory");
    __builtin_amdgcn_s_barrier();
    __builtin_amdgcn_sched_barrier(0);
}

// ---------------- prep: 3x Wih transpose to [(k/4)][768][4] ----------------
__global__ void k_prep(const float* eWih, const float* tWih, const float* dWih,
                       float* d0, float* d1, float* d2) {
    int which = blockIdx.y;
    const float* s = which == 0 ? eWih : (which == 1 ? tWih : dWih);
    float* d = which == 0 ? d0 : (which == 1 ? d1 : d2);
    int n = blockIdx.x;
    for (int k = threadIdx.x; k < H; k += 256)
        d[(size_t)(k >> 2) * (H3 * 4) + n * 4 + (k & 3)] = s[(size_t)n * H + k];
}

// ---------------- gi(enc,tag) + Whh->frags + proj transpose ----------------
// blocks [0,210): gi enc/tag; [210,498): Whh frags; [498,754): proj transpose
// frag order (16-wave): out[w16][f][lane][8], f = ks*3+q,
//   row = q*256 + w16*16 + (lane&15), k = ks*32 + (lane>>4)*8
__global__ __launch_bounds__(256) void k_gi_prep(
    const int* in_toks, const int* tag_toks, const float* enc_emb,
    const float* tag_emb, const float* W4e, const float* W4t,
    const float* bih_e, const float* bhh_e, const float* bih_t,
    const float* bhh_t, __hip_bfloat16* gi_e, __hip_bfloat16* gi_t,
    const float* eWhh, const float* tWhh, const float* dWhh,
    __hip_bfloat16* p0, __hip_bfloat16* p1, __hip_bfloat16* p2,
    const float* projW, float* W4_proj) {
    int bx = blockIdx.x, tid = threadIdx.x;
    if (bx >= 498) {
        int n = bx - 498;  // proj transpose: [256][512] -> [(k/4)][256][4]
        for (int k = tid; k < 2 * H; k += 256)
            W4_proj[(size_t)(k >> 2) * 1024 + n * 4 + (k & 3)] =
                projW[(size_t)n * 2 * H + k];
        return;
    }
    if (bx >= NGIET) {
        int wb = bx - NGIET;
        int m = wb / 96;
        const float* s = m == 0 ? eWhh : (m == 1 ? tWhh : dWhh);
        __hip_bfloat16* d = m == 0 ? p0 : (m == 1 ? p1 : p2);
        int idx = (wb % 96) * 256 + tid;  // 0..24575
        int lane = idx & 63;
        int f = (idx >> 6) % 24;
        int w = idx / (24 * 64);
        int ks = f / 3, q = f % 3;
        int row = (q << 8) + (w << 4) + (lane & 15);
        int k = (ks << 5) + ((lane >> 4) << 3);
#pragma unroll
        for (int j = 0; j < 8; ++j)
            d[(size_t)idx * 8 + j] = __float2bfloat16(s[(size_t)row * H + k + j]);
        return;
    }
    __shared__ float x[NBATCH][H];
    int g = bx % 3, tt = bx / 3;
    const int* toks;
    const float* emb;
    const float* W4;
    const float* bihp;
    const float* bhhp;
    __hip_bfloat16* gip;
    int t;
    if (tt < TIN) {
        toks = in_toks; emb = enc_emb; W4 = W4e; bihp = bih_e; bhhp = bhh_e;
        gip = gi_e; t = tt;
    } else {
        toks = tag_toks; emb = tag_emb; W4 = W4t; bihp = bih_t; bhhp = bhh_t;
        gip = gi_t; t = tt - TIN;
    }
    for (int b = 0; b < NBATCH; ++b)
        x[b][tid] = emb[(size_t)toks[t * NBATCH + b] * H + tid];
    __syncthreads();
    int nb_ = tid & 63, mg = tid >> 6;
    float acc[4][8];
#pragma unroll
    for (int j = 0; j < 4; ++j)
#pragma unroll
        for (int mi = 0; mi < 8; ++mi) acc[j][mi] = 0.f;
    for (int k4 = 0; k4 < 64; ++k4) {
        const float4* wrow = (const float4*)(W4 + (size_t)k4 * 3072);
        float4 w0 = wrow[g * 256 + nb_];
        float4 w1 = wrow[g * 256 + nb_ + 64];
        float4 w2 = wrow[g * 256 + nb_ + 128];
        float4 w3 = wrow[g * 256 + nb_ + 192];
#pragma unroll
        for (int mi = 0; mi < 8; ++mi) {
            float4 xv = *(const float4*)&x[mg * 8 + mi][k4 * 4];
            acc[0][mi] += dot4(xv, w0);
            acc[1][mi] += dot4(xv, w1);
            acc[2][mi] += dot4(xv, w2);
            acc[3][mi] += dot4(xv, w3);
        }
    }
#pragma unroll
    for (int j = 0; j < 4; ++j) {
        int n = g * 256 + nb_ + j * 64;
        float bv = bihp[n] + (g < 2 ? bhhp[n] : 0.0f);
        int nn = n & 255;
        int ww = nn >> 4, lrr = nn & 15;
#pragma unroll
        for (int mi = 0; mi < 8; ++mi) {
            int bm = mg * 8 + mi;
            int locb = bm >> 4, lmm = bm & 15;
            int lgg = lmm >> 2, reg = lmm & 3;
            size_t idx = ((size_t)(t * 2 + locb) * 16 + ww) * 1024 +
                         reg * 256 + (lgg * 16 + lrr) * 4 + g;
            gip[idx] = __float2bfloat16(acc[j][mi] + bv);
        }
    }
}

// ---------------- enc+tag scan + free-riding gi_dec / outW-cvt blocks ------
// blocks 0-3: scan (2 enc + 2 tag).  blocks 4..43: gi_dec (t = blk-4).
// blocks 44..547: outW->bf16 grid-stride cvt.  No cross-block dependencies.
__global__ __launch_bounds__(1024) void k_scan_enc(
    const __hip_bfloat16* gi1, const __hip_bfloat16* W1, const float* bhh1,
    float* hT1, int T1,
    const __hip_bfloat16* gi2, const __hip_bfloat16* W2, const float* bhh2,
    float* hT2, int T2,
    const int* tgt_toks, const float* enc_emb, const float* W4d,
    const float* bih_d, const float* bhh_d, __hip_bfloat16* gi_d,
    const float* outW, __hip_bfloat16* outWb) {
    __shared__ uint4 WL[16 * 6 * 64];  // 96KB
    __shared__ uint4 HBF[2][512];      // 16KB

    int blk = blockIdx.x, tid = threadIdx.x;
    if (blk >= 4) {
        int wb = blk - 4;
        if (wb < TTGT) {
            // ---- gi_dec for t = wb (768 active threads, shared x) ----
            int t = wb;
            float* x = (float*)WL;  // [32][256] = 32KB
            if (tid < 256) {
                for (int b = 0; b < NBATCH; ++b) {
                    int tok = (t == 0) ? 1 : tgt_toks[(t - 1) * NBATCH + b];
                    x[b * 256 + tid] = fmaxf(enc_emb[(size_t)tok * H + tid], 0.0f);
                }
            }
            __syncthreads();
            if (tid < 768) {
                int g = tid >> 8, tidg = tid & 255;
                int nb_ = tidg & 63, mg = tidg >> 6;
                float acc[4][8];
#pragma unroll
                for (int j = 0; j < 4; ++j)
#pragma unroll
                    for (int mi = 0; mi < 8; ++mi) acc[j][mi] = 0.f;
                for (int k4 = 0; k4 < 64; ++k4) {
                    const float4* wrow = (const float4*)(W4d + (size_t)k4 * 3072);
                    float4 w0 = wrow[g * 256 + nb_];
                    float4 w1 = wrow[g * 256 + nb_ + 64];
                    float4 w2 = wrow[g * 256 + nb_ + 128];
                    float4 w3 = wrow[g * 256 + nb_ + 192];
#pragma unroll
                    for (int mi = 0; mi < 8; ++mi) {
                        float4 xv = *(const float4*)&x[(mg * 8 + mi) * 256 + k4 * 4];
                        acc[0][mi] += dot4(xv, w0);
                        acc[1][mi] += dot4(xv, w1);
                        acc[2][mi] += dot4(xv, w2);
                        acc[3][mi] += dot4(xv, w3);
                    }
                }
#pragma unroll
                for (int j = 0; j < 4; ++j) {
                    int n = g * 256 + nb_ + j * 64;
                    float bv = bih_d[n] + (g < 2 ? bhh_d[n] : 0.0f);
                    int nn = n & 255;
                    int ww = nn >> 4, lrr = nn & 15;
#pragma unroll
                    for (int mi = 0; mi < 8; ++mi) {
                        int bm = mg * 8 + mi;
                        int locb = bm >> 4, lmm = bm & 15;
                        int lgg = lmm >> 2, reg = lmm & 3;
                        size_t idx = ((size_t)(t * 2 + locb) * 16 + ww) * 1024 +
                                     reg * 256 + (lgg * 16 + lrr) * 4 + g;
                        gi_d[idx] = __float2bfloat16(acc[j][mi] + bv);
                    }
                }
            }
            return;
        }
        // ---- outW -> bf16 padded, grid-stride float4 ----
        const size_t total = (size_t)VP * H / 4;
        const size_t stride = (size_t)NCVT2 * 1024;
        for (size_t i = (size_t)(wb - TTGT) * 1024 + tid; i < total; i += stride) {
            size_t i4 = i * 4;
            int row = (int)(i4 >> 8);
            float4 v;
            if (row < VSZ) v = *(const float4*)(outW + i4);
            else v = make_float4(0.f, 0.f, 0.f, 0.f);
            outWb[i4 + 0] = __float2bfloat16(v.x);
            outWb[i4 + 1] = __float2bfloat16(v.y);
            outWb[i4 + 2] = __float2bfloat16(v.z);
            outWb[i4 + 3] = __float2bfloat16(v.w);
        }
        return;
    }

    // ================= scan (blocks 0-3) =================
    const __hip_bfloat16 *gip, *Wg;
    const float* bhh;
    float* hTp;
    int T, loc;
    if (blk < 2) {
        gip = gi1; Wg = W1; bhh = bhh1; hTp = hT1; T = T1; loc = blk;
    } else {
        gip = gi2; Wg = W2; bhh = bhh2; hTp = hT2; T = T2; loc = blk - 2;
    }
    int mb = loc * 16;
    int w = tid >> 6, lane = tid & 63, lr = lane & 15, lg = lane >> 4;

    short8 wreg[18];
    const uint4* Wg4 = (const uint4*)Wg;
#pragma unroll
    for (int f = 0; f < 18; ++f) {
        uint4 v = Wg4[(size_t)(w * 24 + f) * 64 + lane];
        wreg[f] = *(short8*)&v;
    }
#pragma unroll
    for (int i = 0; i < 6; ++i)
        WL[(w * 6 + i) * 64 + lane] = Wg4[(size_t)(w * 24 + 18 + i) * 64 + lane];

    float bnv = bhh[512 + w * 16 + lr];

    float hprev[4];
    short* HB16 = (short*)HBF;
#pragma unroll
    for (int reg = 0; reg < 4; ++reg) {
        int row = lg * 4 + reg;
        hprev[reg] = 0.0f;
        int ch = w * 2 + (lr >> 3);
        int slot = ch ^ (row & 7);
        HB16[row * 256 + slot * 8 + (lr & 7)] = 0;
    }
    uint2 gv[4];
    {
        const __hip_bfloat16* gp = gip + ((size_t)loc * 16 + w) * 1024;
#pragma unroll
        for (int reg = 0; reg < 4; ++reg)
            gv[reg] = *(const uint2*)(gp + reg * 256 + lane * 4);
    }
    __syncthreads();

    const short8* HSbase = (const short8*)HBF;
    const short8* WLs = (const short8*)WL;
    for (int t = 0; t < T; ++t) {
        int p = t & 1, p2 = p ^ 1;
        const short8* HS = HSbase + p * 512;
        f32x4 acc[3];
        acc[0] = (f32x4){0.f, 0.f, 0.f, 0.f};
        acc[1] = acc[0];
        acc[2] = (f32x4){bnv, bnv, bnv, bnv};
#pragma unroll
        for (int ks = 0; ks < 6; ++ks) {
            short8 a = HS[lr * 32 + ((ks * 4 + lg) ^ (lr & 7))];
#pragma unroll
            for (int q = 0; q < 3; ++q)
                acc[q] = __builtin_amdgcn_mfma_f32_16x16x32_bf16(
                    a, wreg[ks * 3 + q], acc[q], 0, 0, 0);
        }
#pragma unroll
        for (int ks = 6; ks < 8; ++ks) {
            short8 a = HS[lr * 32 + ((ks * 4 + lg) ^ (lr & 7))];
#pragma unroll
            for (int q = 0; q < 3; ++q) {
                short8 bv = WLs[(w * 6 + (ks - 6) * 3 + q) * 64 + lane];
                acc[q] = __builtin_amdgcn_mfma_f32_16x16x32_bf16(
                    a, bv, acc[q], 0, 0, 0);
            }
        }
#pragma unroll
        for (int reg = 0; reg < 4; ++reg) {
            uint2 u = gv[reg];
            float gr = bf2f((short)(u.x & 0xffff));
            float gz = bf2f((short)(u.x >> 16));
            float gn = bf2f((short)(u.y & 0xffff));
            float er = __expf(-(gr + acc[0][reg]));
            float r = __builtin_amdgcn_rcpf(1.0f + er);
            float ez = __expf(-(gz + acc[1][reg]));
            float z = __builtin_amdgcn_rcpf(1.0f + ez);
            float xx = gn + r * acc[2][reg];
            float e2 = __expf(-2.0f * fabsf(xx));
            float nv = copysignf((1.0f - e2) * __builtin_amdgcn_rcpf(1.0f + e2), xx);
            float hnew = (1.0f - z) * nv + z * hprev[reg];
            hprev[reg] = hnew;
            __hip_bfloat16 qb = __float2bfloat16(hnew);
            int row = lg * 4 + reg;
            int ch = w * 2 + (lr >> 3);
            int slot = ch ^ (row & 7);
            HB16[p2 * 4096 + row * 256 + slot * 8 + (lr & 7)] = *(short*)&qb;
        }
        if (t + 1 < T) {
            const __hip_bfloat16* gp =
                gip + ((size_t)((t + 1) * 2 + loc) * 16 + w) * 1024;
#pragma unroll
            for (int reg = 0; reg < 4; ++reg)
                gv[reg] = *(const uint2*)(gp + reg * 256 + lane * 4);
        }
        bar_lgkm();
    }
    if (hTp) {
#pragma unroll
        for (int reg = 0; reg < 4; ++reg) {
            int row = lg * 4 + reg, col = w * 16 + lr;
            hTp[(size_t)(mb + row) * H + col] = hprev[reg];
        }
    }
}

// ---------------- dec scan with in-LDS proj (2 blocks x 1024) --------------
__global__ __launch_bounds__(1024) void k_scan_dec(
    const __hip_bfloat16* gip, const __hip_bfloat16* Wg, const float* bhh,
    __hip_bfloat16* outp, int T,
    const float* tagh, const float* ench, const float* W4p, const float* pb) {
    __shared__ uint4 WL[16 * 6 * 64];  // 96KB
    __shared__ uint4 HBF[2][512];      // 16KB

    int blk = blockIdx.x, tid = threadIdx.x;
    int loc = blk, mb = loc * 16;
    int w = tid >> 6, lane = tid & 63, lr = lane & 15, lg = lane >> 4;

    // ---- proj: merged = concat(tagh,ench) @ W4p^T + pb (in WL space) ----
    float* CC = (float*)WL;            // [16][512]
    float* MM = ((float*)WL) + 8192;   // [16][256]
#pragma unroll
    for (int i = 0; i < 8; ++i) {
        int idx = i * 1024 + tid;
        int row = idx >> 9, col = idx & 511;
        float v = (col < 256) ? tagh[(size_t)(mb + row) * H + col]
                              : ench[(size_t)(mb + row) * H + (col - 256)];
        CC[idx] = v;
    }
    __syncthreads();
    {
        int col = tid & 255, rg = tid >> 8;
        float a0 = 0.f, a1 = 0.f, a2 = 0.f, a3 = 0.f;
        for (int k4 = 0; k4 < 128; ++k4) {
            float4 wv = ((const float4*)(W4p + (size_t)k4 * 1024))[col];
            float4 c0 = *(const float4*)&CC[(rg * 4 + 0) * 512 + k4 * 4];
            float4 c1 = *(const float4*)&CC[(rg * 4 + 1) * 512 + k4 * 4];
            float4 c2 = *(const float4*)&CC[(rg * 4 + 2) * 512 + k4 * 4];
            float4 c3 = *(const float4*)&CC[(rg * 4 + 3) * 512 + k4 * 4];
            a0 += dot4(c0, wv);
            a1 += dot4(c1, wv);
            a2 += dot4(c2, wv);
            a3 += dot4(c3, wv);
        }
        float bv = pb[col];
        __syncthreads();
        MM[(rg * 4 + 0) * 256 + col] = a0 + bv;
        MM[(rg * 4 + 1) * 256 + col] = a1 + bv;
        MM[(rg * 4 + 2) * 256 + col] = a2 + bv;
        MM[(rg * 4 + 3) * 256 + col] = a3 + bv;
    }
    __syncthreads();

    float hprev[4];
    short* HB16 = (short*)HBF;
#pragma unroll
    for (int reg = 0; reg < 4; ++reg) {
        int row = lg * 4 + reg, col = w * 16 + lr;
        float hv = MM[row * 256 + col];
        hprev[reg] = hv;
        __hip_bfloat16 q = __float2bfloat16(hv);
        int ch = w * 2 + (lr >> 3);
        int slot = ch ^ (row & 7);
        HB16[row * 256 + slot * 8 + (lr & 7)] = *(short*)&q;
    }
    __syncthreads();  // MM reads done before WL overwrite

    short8 wreg[18];
    const uint4* Wg4 = (const uint4*)Wg;
#pragma unroll
    for (int f = 0; f < 18; ++f) {
        uint4 v = Wg4[(size_t)(w * 24 + f) * 64 + lane];
        wreg[f] = *(short8*)&v;
    }
#pragma unroll
    for (int i = 0; i < 6; ++i)
        WL[(w * 6 + i) * 64 + lane] = Wg4[(size_t)(w * 24 + 18 + i) * 64 + lane];

    float bnv = bhh[512 + w * 16 + lr];

    uint2 gv[4];
    {
        const __hip_bfloat16* gp = gip + ((size_t)loc * 16 + w) * 1024;
#pragma unroll
        for (int reg = 0; reg < 4; ++reg)
            gv[reg] = *(const uint2*)(gp + reg * 256 + lane * 4);
    }
    __syncthreads();

    const short8* HSbase = (const short8*)HBF;
    const short8* WLs = (const short8*)WL;
    for (int t = 0; t < T; ++t) {
        int p = t & 1, p2 = p ^ 1;
        const short8* HS = HSbase + p * 512;
        f32x4 acc[3];
        acc[0] = (f32x4){0.f, 0.f, 0.f, 0.f};
        acc[1] = acc[0];
        acc[2] = (f32x4){bnv, bnv, bnv, bnv};
#pragma unroll
        for (int ks = 0; ks < 6; ++ks) {
            short8 a = HS[lr * 32 + ((ks * 4 + lg) ^ (lr & 7))];
#pragma unroll
            for (int q = 0; q < 3; ++q)
                acc[q] = __builtin_amdgcn_mfma_f32_16x16x32_bf16(
                    a, wreg[ks * 3 + q], acc[q], 0, 0, 0);
        }
#pragma unroll
        for (int ks = 6; ks < 8; ++ks) {
            short8 a = HS[lr * 32 + ((ks * 4 + lg) ^ (lr & 7))];
#pragma unroll
            for (int q = 0; q < 3; ++q) {
                short8 bv = WLs[(w * 6 + (ks - 6) * 3 + q) * 64 + lane];
                acc[q] = __builtin_amdgcn_mfma_f32_16x16x32_bf16(
                    a, bv, acc[q], 0, 0, 0);
            }
        }
#pragma unroll
        for (int reg = 0; reg < 4; ++reg) {
            uint2 u = gv[reg];
            float gr = bf2f((short)(u.x & 0xffff));
            float gz = bf2f((short)(u.x >> 16));
            float gn = bf2f((short)(u.y & 0xffff));
            float er = __expf(-(gr + acc[0][reg]));
            float r = __builtin_amdgcn_rcpf(1.0f + er);
            float ez = __expf(-(gz + acc[1][reg]));
            float z = __builtin_amdgcn_rcpf(1.0f + ez);
            float xx = gn + r * acc[2][reg];
            float e2 = __expf(-2.0f * fabsf(xx));
            float nv = copysignf((1.0f - e2) * __builtin_amdgcn_rcpf(1.0f + e2), xx);
            float hnew = (1.0f - z) * nv + z * hprev[reg];
            hprev[reg] = hnew;
            __hip_bfloat16 qb = __float2bfloat16(hnew);
            int row = lg * 4 + reg;
            int ch = w * 2 + (lr >> 3);
            int slot = ch ^ (row & 7);
            HB16[p2 * 4096 + row * 256 + slot * 8 + (lr & 7)] = *(short*)&qb;
        }
        if (t + 1 < T) {
            const __hip_bfloat16* gp =
                gip + ((size_t)((t + 1) * 2 + loc) * 16 + w) * 1024;
#pragma unroll
            for (int reg = 0; reg < 4; ++reg)
                gv[reg] = *(const uint2*)(gp + reg * 256 + lane * 4);
        }
        if (t >= 1 && tid < 512) {
            int lb = tid >> 5, ch2 = tid & 31;
            short8 hv = HSbase[p * 512 + lb * 32 + (ch2 ^ (lb & 7))];
            *(short8*)(outp + (size_t)((t - 1) * NBATCH + mb + lb) * H + ch2 * 8) = hv;
        }
        bar_lgkm();
    }
    if (tid < 512) {
        int lb = tid >> 5, ch2 = tid & 31;
        short8 hv = HSbase[(T & 1) * 512 + lb * 32 + (ch2 ^ (lb & 7))];
        *(short8*)(outp + (size_t)((T - 1) * NBATCH + mb + lb) * H + ch2 * 8) = hv;
    }
}

// ---------------- logits GEMM: C[1280][50003] = A @ Bw^T + bias ------------
__global__ __launch_bounds__(256) void k_logits(const __hip_bfloat16* A,
                                                const __hip_bfloat16* Bw,
                                                const float* bias, float* dout,
                                                float* pmax, float* psum) {
    __shared__ uint4 bsm[2048];       // 32KB B tile
    __shared__ float cst[4][16][68];  // 17KB per-wave C staging
    int bid = blockIdx.x;
    int wg = (bid & 7) * 1955 + (bid >> 3);  // XCD-aware bijective swizzle
    int nblk = wg / 20, mblk = wg % 20;      // N-major: 20 M-tiles per B-tile
    int m0 = mblk * 64, n0 = nblk * 64;
    int tid = threadIdx.x;
    int wave = tid >> 6, lane = tid & 63, lr = lane & 15, lg = lane >> 4;
    const uint4* Bg = (const uint4*)(Bw + (size_t)n0 * H);
#pragma unroll
    for (int i = 0; i < 8; ++i) {
        int c = tid + i * 256;
        int r = c >> 5, g = c & 31;
        bsm[(r << 5) | (g ^ (r & 7))] = Bg[c];
    }
    short8 areg[8];
    const uint4* Ar = (const uint4*)(A + (size_t)(m0 + wave * 16 + lr) * H);
#pragma unroll
    for (int ks = 0; ks < 8; ++ks) {
        uint4 v = Ar[ks * 4 + lg];
        areg[ks] = *(short8*)&v;
    }
    float biasv[4];
    bool valid[4];
#pragma unroll
    for (int ns = 0; ns < 4; ++ns) {
        int n = n0 + ns * 16 + lr;
        valid[ns] = (n < VSZ);
        biasv[ns] = valid[ns] ? bias[n] : 0.f;
    }
    __syncthreads();
    f32x4 acc[4];
#pragma unroll
    for (int ns = 0; ns < 4; ++ns) acc[ns] = (f32x4){0.f, 0.f, 0.f, 0.f};
    const short8* L = (const short8*)bsm;
#pragma unroll
    for (int ks = 0; ks < 8; ++ks) {
        int ga = ks * 4 + lg;
#pragma unroll
        for (int ns = 0; ns < 4; ++ns) {
            int rb = ns * 16 + lr;
            acc[ns] = __builtin_amdgcn_mfma_f32_16x16x32_bf16(
                areg[ks], L[(rb << 5) | (ga ^ (rb & 7))], acc[ns], 0, 0, 0);
        }
    }
    float* cw = &cst[wave][0][0];
#pragma unroll
    for (int reg = 0; reg < 4; ++reg) {
        int m = m0 + wave * 16 + lg * 4 + reg;
        float v[4];
        float rm = -INFINITY;
#pragma unroll
        for (int ns = 0; ns < 4; ++ns) {
            v[ns] = acc[ns][reg] + biasv[ns];
            if (valid[ns]) rm = fmaxf(rm, v[ns]);
            cw[(lg * 4 + reg) * 68 + ns * 16 + lr] = v[ns];
        }
        for (int off = 1; off < 16; off <<= 1) rm = fmaxf(rm, __shfl_xor(rm, off));
        float se = 0.f;
#pragma unroll
        for (int ns = 0; ns < 4; ++ns)
            if (valid[ns]) se += __expf(v[ns] - rm);
        for (int off = 1; off < 16; off <<= 1) se += __shfl_xor(se, off);
        if (lr == 0) {
            pmax[(size_t)m * NT + nblk] = rm;
            psum[(size_t)m * NT + nblk] = se;
        }
    }
    float* dbase = dout + 2 + (size_t)(m0 + wave * 16) * VSZ + n0;
    int c0 = lr * 4;
    bool full = (n0 + c0 + 3 < VSZ);
#pragma unroll
    for (int it = 0; it < 4; ++it) {
        int row = it * 4 + lg;
        f32x4 v4 = *(const f32x4*)&cst[wave][row][c0];
        float* p = dbase + (size_t)row * VSZ + c0;
        if (full) {
            __builtin_memcpy(p, &v4, 16);
        } else {
#pragma unroll
            for (int j = 0; j < 4; ++j)
                if (n0 + c0 + j < VSZ) p[j] = v4[j];
        }
    }
}

// ---------------- per-row logsumexp from tile partials ---------------------
__global__ void k_lse(const float* pmax, const float* psum, float* lse) {
    int m = blockIdx.x, tid = threadIdx.x;
    __shared__ float sm[4];
    float lm = -INFINITY;
    for (int i = tid; i < NT; i += 256) lm = fmaxf(lm, pmax[(size_t)m * NT + i]);
    for (int off = 1; off < 64; off <<= 1) lm = fmaxf(lm, __shfl_xor(lm, off));
    if ((tid & 63) == 0) sm[tid >> 6] = lm;
    __syncthreads();
    float M = fmaxf(fmaxf(sm[0], sm[1]), fmaxf(sm[2], sm[3]));
    __syncthreads();
    float s = 0.f;
    for (int i = tid; i < NT; i += 256)
        s += psum[(size_t)m * NT + i] * __expf(pmax[(size_t)m * NT + i] - M);
    for (int off = 1; off < 64; off <<= 1) s += __shfl_xor(s, off);
    if ((tid & 63) == 0) sm[tid >> 6] = s;
    __syncthreads();
    if (tid == 0) lse[m] = M + logf(sm[0] + sm[1] + sm[2] + sm[3]);
}

// ---------------- final NLL loss -------------------------------------------
__global__ void k_loss(const float* lse, const int* tgt, float* dout) {
    int tid = threadIdx.x;
    __shared__ float sm[4];
    float s = 0.f;
    for (int m = tid; m < MT; m += 256) {
        int tg = tgt[m];
        s += lse[m] - dout[2 + (size_t)m * VSZ + tg];
    }
    for (int off = 1; off < 64; off <<= 1) s += __shfl_xor(s, off);
    if ((tid & 63) == 0) sm[tid >> 6] = s;
    __syncthreads();
    if (tid == 0) {
        float total = sm[0] + sm[1] + sm[2] + sm[3];
        dout[0] = total / 32.0f;    // sum over t of mean over batch
        dout[1] = total / 1280.0f;  // / T_tgt
    }
}

// ---------------------------------------------------------------------------
extern "C" void kernel_launch(void* const* d_in, const int* in_sizes, int n_in,
                              void* d_out, int out_size, void* d_ws,
                              size_t ws_size, hipStream_t stream) {
    const int* input_tensor = (const int*)d_in[0];
    const int* target_tensor = (const int*)d_in[1];
    const int* tag_tensor = (const int*)d_in[2];
    const float* enc_emb = (const float*)d_in[3];
    const float* enc_Wih = (const float*)d_in[4];
    const float* enc_Whh = (const float*)d_in[5];
    const float* enc_bih = (const float*)d_in[6];
    const float* enc_bhh = (const float*)d_in[7];
    const float* tag_emb = (const float*)d_in[8];
    const float* tag_Wih = (const float*)d_in[9];
    const float* tag_Whh = (const float*)d_in[10];
    const float* tag_bih = (const float*)d_in[11];
    const float* tag_bhh = (const float*)d_in[12];
    const float* proj_W = (const float*)d_in[13];
    const float* proj_b = (const float*)d_in[14];
    const float* dec_Wih = (const float*)d_in[15];
    const float* dec_Whh = (const float*)d_in[16];
    const float* dec_bih = (const float*)d_in[17];
    const float* dec_bhh = (const float*)d_in[18];
    const float* out_W = (const float*)d_in[19];
    const float* out_b = (const float*)d_in[20];

    char* wsb = (char*)d_ws;
    size_t o = 0;
    auto alloc = [&](size_t bytes) {
        size_t r = o;
        o += (bytes + 511) & ~(size_t)511;
        return r;
    };
    float* W4_enc_ih = (float*)(wsb + alloc(H3 * H * 4));
    float* W4_tag_ih = (float*)(wsb + alloc(H3 * H * 4));
    float* W4_dec_ih = (float*)(wsb + alloc(H3 * H * 4));
    float* W4_proj   = (float*)(wsb + alloc(H * 2 * H * 4));
    __hip_bfloat16* gi_enc = (__hip_bfloat16*)(wsb + alloc((size_t)TIN * 65536));
    __hip_bfloat16* gi_tag = (__hip_bfloat16*)(wsb + alloc((size_t)TTAG * 65536));
    __hip_bfloat16* gi_dec = (__hip_bfloat16*)(wsb + alloc((size_t)TTGT * 65536));
    float* enc_h  = (float*)(wsb + alloc(NBATCH * H * 4));
    float* tag_h  = (float*)(wsb + alloc(NBATCH * H * 4));
    float* lse    = (float*)(wsb + alloc(MT * 4));
    __hip_bfloat16* Wp_enc = (__hip_bfloat16*)(wsb + alloc(H3 * H * 2));
    __hip_bfloat16* Wp_tag = (__hip_bfloat16*)(wsb + alloc(H3 * H * 2));
    __hip_bfloat16* Wp_dec = (__hip_bfloat16*)(wsb + alloc(H3 * H * 2));
    __hip_bfloat16* outWb  = (__hip_bfloat16*)(wsb + alloc((size_t)VP * H * 2));
    __hip_bfloat16* decA   = (__hip_bfloat16*)(wsb + alloc((size_t)MT * H * 2));
    float* pmax = (float*)(wsb + alloc((size_t)MT * NT * 4));
    float* psum = (float*)(wsb + alloc((size_t)MT * NT * 4));

    float* dout = (float*)d_out;

    // 1) Wih transposes (needed by gi)
    k_prep<<<dim3(H3, 3), 256, 0, stream>>>(enc_Wih, tag_Wih, dec_Wih,
                                            W4_enc_ih, W4_tag_ih, W4_dec_ih);

    // 2) gi(enc,tag) + Whh->frags + proj transpose
    k_gi_prep<<<754, 256, 0, stream>>>(
        input_tensor, tag_tensor, enc_emb, tag_emb, W4_enc_ih, W4_tag_ih,
        enc_bih, enc_bhh, tag_bih, tag_bhh, gi_enc, gi_tag,
        enc_Whh, tag_Whh, dec_Whh, Wp_enc, Wp_tag, Wp_dec, proj_W, W4_proj);

    // 3) enc+tag scans + free-riding gi_dec + outW cvt (548 blocks)
    k_scan_enc<<<4 + TTGT + NCVT2, 1024, 0, stream>>>(
        gi_enc, Wp_enc, enc_bhh, enc_h, TIN,
        gi_tag, Wp_tag, tag_bhh, tag_h, TTAG,
        target_tensor, enc_emb, W4_dec_ih, dec_bih, dec_bhh, gi_dec,
        out_W, outWb);

    // 4) dec scan with in-LDS proj (2 blocks)
    k_scan_dec<<<2, 1024, 0, stream>>>(gi_dec, Wp_dec, dec_bhh, decA, TTGT,
                                       tag_h, enc_h, W4_proj, proj_b);

    // 5) logits GEMM + LSE partials (grid = 782*20)
    k_logits<<<NT * 20, 256, 0, stream>>>(decA, outWb, out_b, dout, pmax, psum);

    // 6) per-row logsumexp
    k_lse<<<MT, 256, 0, stream>>>(pmax, psum, lse);

    // 7) loss scalars
    k_loss<<<1, 256, 0, stream>>>(lse, target_tensor, dout);
}

// Round 17
// 414.616 us; speedup vs baseline: 1.3891x; 1.0214x over previous
//
#include <hip/hip_runtime.h>
#include <hip/hip_bf16.h>
#include <math.h>

// ---------------------------------------------------------------------------
// Seq2Seq: enc GRU (T=50) + tag GRU (T=20) -> proj -> dec GRU (T=40)
//          -> logits GEMM (1280x50003, K=256, bf16 MFMA) -> LSE -> NLL loss
//
// Round 17: A/B on the proj-fold.  r16's profile caught k_scan_dec at
// 224.6us with VGPR_Count=64 (wreg[18]=72 regs can't fit -> suspected
// spill from the fused in-LDS proj prologue perturbing regalloc).
// Single change vs r16: proj un-fused into its own 32-block kernel;
// k_scan_dec hot loop now compiles identically to the clean scan.
// ---------------------------------------------------------------------------

#define H 256
#define H3 768
#define NBATCH 32
#define TIN 50
#define TTGT 40
#define TTAG 20
#define VSZ 50003
#define VP 50048          // padded to 64
#define NT 782            // VP / 64
#define MT 1280           // TTGT * NBATCH
#define NGIET 210         // (50+20) timesteps * 3 gates
#define NCVT2 504         // outW cvt worker blocks (1024 thr, grid-stride)

typedef float f32x4 __attribute__((ext_vector_type(4)));
typedef short short8 __attribute__((ext_vector_type(8)));

__device__ __forceinline__ float dot4(float4 a, float4 b) {
    return a.x * b.x + a.y * b.y + a.z * b.z + a.w * b.w;
}

__device__ __forceinline__ float bf2f(short s) {
    unsigned int u = ((unsigned int)(unsigned short)s) << 16;
    return __builtin_bit_cast(float, u);
}

// barrier with LDS-only drain: leaves global loads in flight
__device__ __forceinline__ void bar_lgkm() {
    asm volatile("s_waitcnt lgkmcnt(0)" ::: "memory");
    __builtin_amdgcn_s_barrier();
    __builtin_amdgcn_sched_barrier(0);
}

// ---------------- prep: 3x Wih transpose to [(k/4)][768][4] ----------------
__global__ void k_prep(const float* eWih, const float* tWih, const float* dWih,
                       float* d0, float* d1, float* d2) {
    int which = blockIdx.y;
    const float* s = which == 0 ? eWih : (which == 1 ? tWih : dWih);
    float* d = which == 0 ? d0 : (which == 1 ? d1 : d2);
    int n = blockIdx.x;
    for (int k = threadIdx.x; k < H; k += 256)
        d[(size_t)(k >> 2) * (H3 * 4) + n * 4 + (k & 3)] = s[(size_t)n * H + k];
}

// ---------------- gi(enc,tag) + Whh->frags + proj transpose ----------------
// blocks [0,210): gi enc/tag; [210,498): Whh frags; [498,754): proj transpose
__global__ __launch_bounds__(256) void k_gi_prep(
    const int* in_toks, const int* tag_toks, const float* enc_emb,
    const float* tag_emb, const float* W4e, const float* W4t,
    const float* bih_e, const float* bhh_e, const float* bih_t,
    const float* bhh_t, __hip_bfloat16* gi_e, __hip_bfloat16* gi_t,
    const float* eWhh, const float* tWhh, const float* dWhh,
    __hip_bfloat16* p0, __hip_bfloat16* p1, __hip_bfloat16* p2,
    const float* projW, float* W4_proj) {
    int bx = blockIdx.x, tid = threadIdx.x;
    if (bx >= 498) {
        int n = bx - 498;  // proj transpose: [256][512] -> [(k/4)][256][4]
        for (int k = tid; k < 2 * H; k += 256)
            W4_proj[(size_t)(k >> 2) * 1024 + n * 4 + (k & 3)] =
                projW[(size_t)n * 2 * H + k];
        return;
    }
    if (bx >= NGIET) {
        int wb = bx - NGIET;
        int m = wb / 96;
        const float* s = m == 0 ? eWhh : (m == 1 ? tWhh : dWhh);
        __hip_bfloat16* d = m == 0 ? p0 : (m == 1 ? p1 : p2);
        int idx = (wb % 96) * 256 + tid;  // 0..24575
        int lane = idx & 63;
        int f = (idx >> 6) % 24;
        int w = idx / (24 * 64);
        int ks = f / 3, q = f % 3;
        int row = (q << 8) + (w << 4) + (lane & 15);
        int k = (ks << 5) + ((lane >> 4) << 3);
#pragma unroll
        for (int j = 0; j < 8; ++j)
            d[(size_t)idx * 8 + j] = __float2bfloat16(s[(size_t)row * H + k + j]);
        return;
    }
    __shared__ float x[NBATCH][H];
    int g = bx % 3, tt = bx / 3;
    const int* toks;
    const float* emb;
    const float* W4;
    const float* bihp;
    const float* bhhp;
    __hip_bfloat16* gip;
    int t;
    if (tt < TIN) {
        toks = in_toks; emb = enc_emb; W4 = W4e; bihp = bih_e; bhhp = bhh_e;
        gip = gi_e; t = tt;
    } else {
        toks = tag_toks; emb = tag_emb; W4 = W4t; bihp = bih_t; bhhp = bhh_t;
        gip = gi_t; t = tt - TIN;
    }
    for (int b = 0; b < NBATCH; ++b)
        x[b][tid] = emb[(size_t)toks[t * NBATCH + b] * H + tid];
    __syncthreads();
    int nb_ = tid & 63, mg = tid >> 6;
    float acc[4][8];
#pragma unroll
    for (int j = 0; j < 4; ++j)
#pragma unroll
        for (int mi = 0; mi < 8; ++mi) acc[j][mi] = 0.f;
    for (int k4 = 0; k4 < 64; ++k4) {
        const float4* wrow = (const float4*)(W4 + (size_t)k4 * 3072);
        float4 w0 = wrow[g * 256 + nb_];
        float4 w1 = wrow[g * 256 + nb_ + 64];
        float4 w2 = wrow[g * 256 + nb_ + 128];
        float4 w3 = wrow[g * 256 + nb_ + 192];
#pragma unroll
        for (int mi = 0; mi < 8; ++mi) {
            float4 xv = *(const float4*)&x[mg * 8 + mi][k4 * 4];
            acc[0][mi] += dot4(xv, w0);
            acc[1][mi] += dot4(xv, w1);
            acc[2][mi] += dot4(xv, w2);
            acc[3][mi] += dot4(xv, w3);
        }
    }
#pragma unroll
    for (int j = 0; j < 4; ++j) {
        int n = g * 256 + nb_ + j * 64;
        float bv = bihp[n] + (g < 2 ? bhhp[n] : 0.0f);
        int nn = n & 255;
        int ww = nn >> 4, lrr = nn & 15;
#pragma unroll
        for (int mi = 0; mi < 8; ++mi) {
            int bm = mg * 8 + mi;
            int locb = bm >> 4, lmm = bm & 15;
            int lgg = lmm >> 2, reg = lmm & 3;
            size_t idx = ((size_t)(t * 2 + locb) * 16 + ww) * 1024 +
                         reg * 256 + (lgg * 16 + lrr) * 4 + g;
            gip[idx] = __float2bfloat16(acc[j][mi] + bv);
        }
    }
}

// ---------------- enc+tag scan + free-riding gi_dec / outW-cvt blocks ------
__global__ __launch_bounds__(1024) void k_scan_enc(
    const __hip_bfloat16* gi1, const __hip_bfloat16* W1, const float* bhh1,
    float* hT1, int T1,
    const __hip_bfloat16* gi2, const __hip_bfloat16* W2, const float* bhh2,
    float* hT2, int T2,
    const int* tgt_toks, const float* enc_emb, const float* W4d,
    const float* bih_d, const float* bhh_d, __hip_bfloat16* gi_d,
    const float* outW, __hip_bfloat16* outWb) {
    __shared__ uint4 WL[16 * 6 * 64];  // 96KB
    __shared__ uint4 HBF[2][512];      // 16KB

    int blk = blockIdx.x, tid = threadIdx.x;
    if (blk >= 4) {
        int wb = blk - 4;
        if (wb < TTGT) {
            // ---- gi_dec for t = wb (768 active threads, shared x) ----
            int t = wb;
            float* x = (float*)WL;  // [32][256] = 32KB
            if (tid < 256) {
                for (int b = 0; b < NBATCH; ++b) {
                    int tok = (t == 0) ? 1 : tgt_toks[(t - 1) * NBATCH + b];
                    x[b * 256 + tid] = fmaxf(enc_emb[(size_t)tok * H + tid], 0.0f);
                }
            }
            __syncthreads();
            if (tid < 768) {
                int g = tid >> 8, tidg = tid & 255;
                int nb_ = tidg & 63, mg = tidg >> 6;
                float acc[4][8];
#pragma unroll
                for (int j = 0; j < 4; ++j)
#pragma unroll
                    for (int mi = 0; mi < 8; ++mi) acc[j][mi] = 0.f;
                for (int k4 = 0; k4 < 64; ++k4) {
                    const float4* wrow = (const float4*)(W4d + (size_t)k4 * 3072);
                    float4 w0 = wrow[g * 256 + nb_];
                    float4 w1 = wrow[g * 256 + nb_ + 64];
                    float4 w2 = wrow[g * 256 + nb_ + 128];
                    float4 w3 = wrow[g * 256 + nb_ + 192];
#pragma unroll
                    for (int mi = 0; mi < 8; ++mi) {
                        float4 xv = *(const float4*)&x[(mg * 8 + mi) * 256 + k4 * 4];
                        acc[0][mi] += dot4(xv, w0);
                        acc[1][mi] += dot4(xv, w1);
                        acc[2][mi] += dot4(xv, w2);
                        acc[3][mi] += dot4(xv, w3);
                    }
                }
#pragma unroll
                for (int j = 0; j < 4; ++j) {
                    int n = g * 256 + nb_ + j * 64;
                    float bv = bih_d[n] + (g < 2 ? bhh_d[n] : 0.0f);
                    int nn = n & 255;
                    int ww = nn >> 4, lrr = nn & 15;
#pragma unroll
                    for (int mi = 0; mi < 8; ++mi) {
                        int bm = mg * 8 + mi;
                        int locb = bm >> 4, lmm = bm & 15;
                        int lgg = lmm >> 2, reg = lmm & 3;
                        size_t idx = ((size_t)(t * 2 + locb) * 16 + ww) * 1024 +
                                     reg * 256 + (lgg * 16 + lrr) * 4 + g;
                        gi_d[idx] = __float2bfloat16(acc[j][mi] + bv);
                    }
                }
            }
            return;
        }
        // ---- outW -> bf16 padded, grid-stride float4 ----
        const size_t total = (size_t)VP * H / 4;
        const size_t stride = (size_t)NCVT2 * 1024;
        for (size_t i = (size_t)(wb - TTGT) * 1024 + tid; i < total; i += stride) {
            size_t i4 = i * 4;
            int row = (int)(i4 >> 8);
            float4 v;
            if (row < VSZ) v = *(const float4*)(outW + i4);
            else v = make_float4(0.f, 0.f, 0.f, 0.f);
            outWb[i4 + 0] = __float2bfloat16(v.x);
            outWb[i4 + 1] = __float2bfloat16(v.y);
            outWb[i4 + 2] = __float2bfloat16(v.z);
            outWb[i4 + 3] = __float2bfloat16(v.w);
        }
        return;
    }

    // ================= scan (blocks 0-3) =================
    const __hip_bfloat16 *gip, *Wg;
    const float* bhh;
    float* hTp;
    int T, loc;
    if (blk < 2) {
        gip = gi1; Wg = W1; bhh = bhh1; hTp = hT1; T = T1; loc = blk;
    } else {
        gip = gi2; Wg = W2; bhh = bhh2; hTp = hT2; T = T2; loc = blk - 2;
    }
    int mb = loc * 16;
    int w = tid >> 6, lane = tid & 63, lr = lane & 15, lg = lane >> 4;

    short8 wreg[18];
    const uint4* Wg4 = (const uint4*)Wg;
#pragma unroll
    for (int f = 0; f < 18; ++f) {
        uint4 v = Wg4[(size_t)(w * 24 + f) * 64 + lane];
        wreg[f] = *(short8*)&v;
    }
#pragma unroll
    for (int i = 0; i < 6; ++i)
        WL[(w * 6 + i) * 64 + lane] = Wg4[(size_t)(w * 24 + 18 + i) * 64 + lane];

    float bnv = bhh[512 + w * 16 + lr];

    float hprev[4];
    short* HB16 = (short*)HBF;
#pragma unroll
    for (int reg = 0; reg < 4; ++reg) {
        int row = lg * 4 + reg;
        hprev[reg] = 0.0f;
        int ch = w * 2 + (lr >> 3);
        int slot = ch ^ (row & 7);
        HB16[row * 256 + slot * 8 + (lr & 7)] = 0;
    }
    uint2 gv[4];
    {
        const __hip_bfloat16* gp = gip + ((size_t)loc * 16 + w) * 1024;
#pragma unroll
        for (int reg = 0; reg < 4; ++reg)
            gv[reg] = *(const uint2*)(gp + reg * 256 + lane * 4);
    }
    __syncthreads();

    const short8* HSbase = (const short8*)HBF;
    const short8* WLs = (const short8*)WL;
    for (int t = 0; t < T; ++t) {
        int p = t & 1, p2 = p ^ 1;
        const short8* HS = HSbase + p * 512;
        f32x4 acc[3];
        acc[0] = (f32x4){0.f, 0.f, 0.f, 0.f};
        acc[1] = acc[0];
        acc[2] = (f32x4){bnv, bnv, bnv, bnv};
#pragma unroll
        for (int ks = 0; ks < 6; ++ks) {
            short8 a = HS[lr * 32 + ((ks * 4 + lg) ^ (lr & 7))];
#pragma unroll
            for (int q = 0; q < 3; ++q)
                acc[q] = __builtin_amdgcn_mfma_f32_16x16x32_bf16(
                    a, wreg[ks * 3 + q], acc[q], 0, 0, 0);
        }
#pragma unroll
        for (int ks = 6; ks < 8; ++ks) {
            short8 a = HS[lr * 32 + ((ks * 4 + lg) ^ (lr & 7))];
#pragma unroll
            for (int q = 0; q < 3; ++q) {
                short8 bv = WLs[(w * 6 + (ks - 6) * 3 + q) * 64 + lane];
                acc[q] = __builtin_amdgcn_mfma_f32_16x16x32_bf16(
                    a, bv, acc[q], 0, 0, 0);
            }
        }
#pragma unroll
        for (int reg = 0; reg < 4; ++reg) {
            uint2 u = gv[reg];
            float gr = bf2f((short)(u.x & 0xffff));
            float gz = bf2f((short)(u.x >> 16));
            float gn = bf2f((short)(u.y & 0xffff));
            float er = __expf(-(gr + acc[0][reg]));
            float r = __builtin_amdgcn_rcpf(1.0f + er);
            float ez = __expf(-(gz + acc[1][reg]));
            float z = __builtin_amdgcn_rcpf(1.0f + ez);
            float xx = gn + r * acc[2][reg];
            float e2 = __expf(-2.0f * fabsf(xx));
            float nv = copysignf((1.0f - e2) * __builtin_amdgcn_rcpf(1.0f + e2), xx);
            float hnew = (1.0f - z) * nv + z * hprev[reg];
            hprev[reg] = hnew;
            __hip_bfloat16 qb = __float2bfloat16(hnew);
            int row = lg * 4 + reg;
            int ch = w * 2 + (lr >> 3);
            int slot = ch ^ (row & 7);
            HB16[p2 * 4096 + row * 256 + slot * 8 + (lr & 7)] = *(short*)&qb;
        }
        if (t + 1 < T) {
            const __hip_bfloat16* gp =
                gip + ((size_t)((t + 1) * 2 + loc) * 16 + w) * 1024;
#pragma unroll
            for (int reg = 0; reg < 4; ++reg)
                gv[reg] = *(const uint2*)(gp + reg * 256 + lane * 4);
        }
        bar_lgkm();
    }
    if (hTp) {
#pragma unroll
        for (int reg = 0; reg < 4; ++reg) {
            int row = lg * 4 + reg, col = w * 16 + lr;
            hTp[(size_t)(mb + row) * H + col] = hprev[reg];
        }
    }
}

// ---------------- merged = concat(tag_h, enc_h) @ proj_W^T + proj_b --------
__global__ void k_proj(const float* tag_h, const float* enc_h,
                       const float* W4p, const float* pb, float* merged) {
    __shared__ float c[2 * H];
    int b = blockIdx.x, tid = threadIdx.x;
    c[tid] = tag_h[b * H + tid];
    c[H + tid] = enc_h[b * H + tid];
    __syncthreads();
    float acc = 0.f;
#pragma unroll 4
    for (int k4 = 0; k4 < 128; ++k4) {
        float4 cv = *(const float4*)&c[k4 * 4];
        float4 wv = ((const float4*)(W4p + (size_t)k4 * 1024))[tid];
        acc += dot4(cv, wv);
    }
    merged[b * H + tid] = acc + pb[tid];
}

// ---------------- dec scan (2 blocks x 1024), h0 from merged ---------------
__global__ __launch_bounds__(1024) void k_scan_dec(
    const __hip_bfloat16* gip, const __hip_bfloat16* Wg, const float* bhh,
    __hip_bfloat16* outp, int T, const float* h0) {
    __shared__ uint4 WL[16 * 6 * 64];  // 96KB
    __shared__ uint4 HBF[2][512];      // 16KB

    int blk = blockIdx.x, tid = threadIdx.x;
    int loc = blk, mb = loc * 16;
    int w = tid >> 6, lane = tid & 63, lr = lane & 15, lg = lane >> 4;

    short8 wreg[18];
    const uint4* Wg4 = (const uint4*)Wg;
#pragma unroll
    for (int f = 0; f < 18; ++f) {
        uint4 v = Wg4[(size_t)(w * 24 + f) * 64 + lane];
        wreg[f] = *(short8*)&v;
    }
#pragma unroll
    for (int i = 0; i < 6; ++i)
        WL[(w * 6 + i) * 64 + lane] = Wg4[(size_t)(w * 24 + 18 + i) * 64 + lane];

    float bnv = bhh[512 + w * 16 + lr];

    float hprev[4];
    short* HB16 = (short*)HBF;
#pragma unroll
    for (int reg = 0; reg < 4; ++reg) {
        int row = lg * 4 + reg, col = w * 16 + lr;
        float hv = h0[(size_t)(mb + row) * H + col];
        hprev[reg] = hv;
        __hip_bfloat16 q = __float2bfloat16(hv);
        int ch = w * 2 + (lr >> 3);
        int slot = ch ^ (row & 7);
        HB16[row * 256 + slot * 8 + (lr & 7)] = *(short*)&q;
    }
    uint2 gv[4];
    {
        const __hip_bfloat16* gp = gip + ((size_t)loc * 16 + w) * 1024;
#pragma unroll
        for (int reg = 0; reg < 4; ++reg)
            gv[reg] = *(const uint2*)(gp + reg * 256 + lane * 4);
    }
    __syncthreads();

    const short8* HSbase = (const short8*)HBF;
    const short8* WLs = (const short8*)WL;
    for (int t = 0; t < T; ++t) {
        int p = t & 1, p2 = p ^ 1;
        const short8* HS = HSbase + p * 512;
        f32x4 acc[3];
        acc[0] = (f32x4){0.f, 0.f, 0.f, 0.f};
        acc[1] = acc[0];
        acc[2] = (f32x4){bnv, bnv, bnv, bnv};
#pragma unroll
        for (int ks = 0; ks < 6; ++ks) {
            short8 a = HS[lr * 32 + ((ks * 4 + lg) ^ (lr & 7))];
#pragma unroll
            for (int q = 0; q < 3; ++q)
                acc[q] = __builtin_amdgcn_mfma_f32_16x16x32_bf16(
                    a, wreg[ks * 3 + q], acc[q], 0, 0, 0);
        }
#pragma unroll
        for (int ks = 6; ks < 8; ++ks) {
            short8 a = HS[lr * 32 + ((ks * 4 + lg) ^ (lr & 7))];
#pragma unroll
            for (int q = 0; q < 3; ++q) {
                short8 bv = WLs[(w * 6 + (ks - 6) * 3 + q) * 64 + lane];
                acc[q] = __builtin_amdgcn_mfma_f32_16x16x32_bf16(
                    a, bv, acc[q], 0, 0, 0);
            }
        }
#pragma unroll
        for (int reg = 0; reg < 4; ++reg) {
            uint2 u = gv[reg];
            float gr = bf2f((short)(u.x & 0xffff));
            float gz = bf2f((short)(u.x >> 16));
            float gn = bf2f((short)(u.y & 0xffff));
            float er = __expf(-(gr + acc[0][reg]));
            float r = __builtin_amdgcn_rcpf(1.0f + er);
            float ez = __expf(-(gz + acc[1][reg]));
            float z = __builtin_amdgcn_rcpf(1.0f + ez);
            float xx = gn + r * acc[2][reg];
            float e2 = __expf(-2.0f * fabsf(xx));
            float nv = copysignf((1.0f - e2) * __builtin_amdgcn_rcpf(1.0f + e2), xx);
            float hnew = (1.0f - z) * nv + z * hprev[reg];
            hprev[reg] = hnew;
            __hip_bfloat16 qb = __float2bfloat16(hnew);
            int row = lg * 4 + reg;
            int ch = w * 2 + (lr >> 3);
            int slot = ch ^ (row & 7);
            HB16[p2 * 4096 + row * 256 + slot * 8 + (lr & 7)] = *(short*)&qb;
        }
        if (t + 1 < T) {
            const __hip_bfloat16* gp =
                gip + ((size_t)((t + 1) * 2 + loc) * 16 + w) * 1024;
#pragma unroll
            for (int reg = 0; reg < 4; ++reg)
                gv[reg] = *(const uint2*)(gp + reg * 256 + lane * 4);
        }
        if (t >= 1 && tid < 512) {
            int lb = tid >> 5, ch2 = tid & 31;
            short8 hv = HSbase[p * 512 + lb * 32 + (ch2 ^ (lb & 7))];
            *(short8*)(outp + (size_t)((t - 1) * NBATCH + mb + lb) * H + ch2 * 8) = hv;
        }
        bar_lgkm();
    }
    if (tid < 512) {
        int lb = tid >> 5, ch2 = tid & 31;
        short8 hv = HSbase[(T & 1) * 512 + lb * 32 + (ch2 ^ (lb & 7))];
        *(short8*)(outp + (size_t)((T - 1) * NBATCH + mb + lb) * H + ch2 * 8) = hv;
    }
}

// ---------------- logits GEMM: C[1280][50003] = A @ Bw^T + bias ------------
__global__ __launch_bounds__(256) void k_logits(const __hip_bfloat16* A,
                                                const __hip_bfloat16* Bw,
                                                const float* bias, float* dout,
                                                float* pmax, float* psum) {
    __shared__ uint4 bsm[2048];       // 32KB B tile
    __shared__ float cst[4][16][68];  // 17KB per-wave C staging
    int bid = blockIdx.x;
    int wg = (bid & 7) * 1955 + (bid >> 3);  // XCD-aware bijective swizzle
    int nblk = wg / 20, mblk = wg % 20;      // N-major: 20 M-tiles per B-tile
    int m0 = mblk * 64, n0 = nblk * 64;
    int tid = threadIdx.x;
    int wave = tid >> 6, lane = tid & 63, lr = lane & 15, lg = lane >> 4;
    const uint4* Bg = (const uint4*)(Bw + (size_t)n0 * H);
#pragma unroll
    for (int i = 0; i < 8; ++i) {
        int c = tid + i * 256;
        int r = c >> 5, g = c & 31;
        bsm[(r << 5) | (g ^ (r & 7))] = Bg[c];
    }
    short8 areg[8];
    const uint4* Ar = (const uint4*)(A + (size_t)(m0 + wave * 16 + lr) * H);
#pragma unroll
    for (int ks = 0; ks < 8; ++ks) {
        uint4 v = Ar[ks * 4 + lg];
        areg[ks] = *(short8*)&v;
    }
    float biasv[4];
    bool valid[4];
#pragma unroll
    for (int ns = 0; ns < 4; ++ns) {
        int n = n0 + ns * 16 + lr;
        valid[ns] = (n < VSZ);
        biasv[ns] = valid[ns] ? bias[n] : 0.f;
    }
    __syncthreads();
    f32x4 acc[4];
#pragma unroll
    for (int ns = 0; ns < 4; ++ns) acc[ns] = (f32x4){0.f, 0.f, 0.f, 0.f};
    const short8* L = (const short8*)bsm;
#pragma unroll
    for (int ks = 0; ks < 8; ++ks) {
        int ga = ks * 4 + lg;
#pragma unroll
        for (int ns = 0; ns < 4; ++ns) {
            int rb = ns * 16 + lr;
            acc[ns] = __builtin_amdgcn_mfma_f32_16x16x32_bf16(
                areg[ks], L[(rb << 5) | (ga ^ (rb & 7))], acc[ns], 0, 0, 0);
        }
    }
    float* cw = &cst[wave][0][0];
#pragma unroll
    for (int reg = 0; reg < 4; ++reg) {
        int m = m0 + wave * 16 + lg * 4 + reg;
        float v[4];
        float rm = -INFINITY;
#pragma unroll
        for (int ns = 0; ns < 4; ++ns) {
            v[ns] = acc[ns][reg] + biasv[ns];
            if (valid[ns]) rm = fmaxf(rm, v[ns]);
            cw[(lg * 4 + reg) * 68 + ns * 16 + lr] = v[ns];
        }
        for (int off = 1; off < 16; off <<= 1) rm = fmaxf(rm, __shfl_xor(rm, off));
        float se = 0.f;
#pragma unroll
        for (int ns = 0; ns < 4; ++ns)
            if (valid[ns]) se += __expf(v[ns] - rm);
        for (int off = 1; off < 16; off <<= 1) se += __shfl_xor(se, off);
        if (lr == 0) {
            pmax[(size_t)m * NT + nblk] = rm;
            psum[(size_t)m * NT + nblk] = se;
        }
    }
    float* dbase = dout + 2 + (size_t)(m0 + wave * 16) * VSZ + n0;
    int c0 = lr * 4;
    bool full = (n0 + c0 + 3 < VSZ);
#pragma unroll
    for (int it = 0; it < 4; ++it) {
        int row = it * 4 + lg;
        f32x4 v4 = *(const f32x4*)&cst[wave][row][c0];
        float* p = dbase + (size_t)row * VSZ + c0;
        if (full) {
            __builtin_memcpy(p, &v4, 16);
        } else {
#pragma unroll
            for (int j = 0; j < 4; ++j)
                if (n0 + c0 + j < VSZ) p[j] = v4[j];
        }
    }
}

// ---------------- per-row logsumexp from tile partials ---------------------
__global__ void k_lse(const float* pmax, const float* psum, float* lse) {
    int m = blockIdx.x, tid = threadIdx.x;
    __shared__ float sm[4];
    float lm = -INFINITY;
    for (int i = tid; i < NT; i += 256) lm = fmaxf(lm, pmax[(size_t)m * NT + i]);
    for (int off = 1; off < 64; off <<= 1) lm = fmaxf(lm, __shfl_xor(lm, off));
    if ((tid & 63) == 0) sm[tid >> 6] = lm;
    __syncthreads();
    float M = fmaxf(fmaxf(sm[0], sm[1]), fmaxf(sm[2], sm[3]));
    __syncthreads();
    float s = 0.f;
    for (int i = tid; i < NT; i += 256)
        s += psum[(size_t)m * NT + i] * __expf(pmax[(size_t)m * NT + i] - M);
    for (int off = 1; off < 64; off <<= 1) s += __shfl_xor(s, off);
    if ((tid & 63) == 0) sm[tid >> 6] = s;
    __syncthreads();
    if (tid == 0) lse[m] = M + logf(sm[0] + sm[1] + sm[2] + sm[3]);
}

// ---------------- final NLL loss -------------------------------------------
__global__ void k_loss(const float* lse, const int* tgt, float* dout) {
    int tid = threadIdx.x;
    __shared__ float sm[4];
    float s = 0.f;
    for (int m = tid; m < MT; m += 256) {
        int tg = tgt[m];
        s += lse[m] - dout[2 + (size_t)m * VSZ + tg];
    }
    for (int off = 1; off < 64; off <<= 1) s += __shfl_xor(s, off);
    if ((tid & 63) == 0) sm[tid >> 6] = s;
    __syncthreads();
    if (tid == 0) {
        float total = sm[0] + sm[1] + sm[2] + sm[3];
        dout[0] = total / 32.0f;    // sum over t of mean over batch
        dout[1] = total / 1280.0f;  // / T_tgt
    }
}

// ---------------------------------------------------------------------------
extern "C" void kernel_launch(void* const* d_in, const int* in_sizes, int n_in,
                              void* d_out, int out_size, void* d_ws,
                              size_t ws_size, hipStream_t stream) {
    const int* input_tensor = (const int*)d_in[0];
    const int* target_tensor = (const int*)d_in[1];
    const int* tag_tensor = (const int*)d_in[2];
    const float* enc_emb = (const float*)d_in[3];
    const float* enc_Wih = (const float*)d_in[4];
    const float* enc_Whh = (const float*)d_in[5];
    const float* enc_bih = (const float*)d_in[6];
    const float* enc_bhh = (const float*)d_in[7];
    const float* tag_emb = (const float*)d_in[8];
    const float* tag_Wih = (const float*)d_in[9];
    const float* tag_Whh = (const float*)d_in[10];
    const float* tag_bih = (const float*)d_in[11];
    const float* tag_bhh = (const float*)d_in[12];
    const float* proj_W = (const float*)d_in[13];
    const float* proj_b = (const float*)d_in[14];
    const float* dec_Wih = (const float*)d_in[15];
    const float* dec_Whh = (const float*)d_in[16];
    const float* dec_bih = (const float*)d_in[17];
    const float* dec_bhh = (const float*)d_in[18];
    const float* out_W = (const float*)d_in[19];
    const float* out_b = (const float*)d_in[20];

    char* wsb = (char*)d_ws;
    size_t o = 0;
    auto alloc = [&](size_t bytes) {
        size_t r = o;
        o += (bytes + 511) & ~(size_t)511;
        return r;
    };
    float* W4_enc_ih = (float*)(wsb + alloc(H3 * H * 4));
    float* W4_tag_ih = (float*)(wsb + alloc(H3 * H * 4));
    float* W4_dec_ih = (float*)(wsb + alloc(H3 * H * 4));
    float* W4_proj   = (float*)(wsb + alloc(H * 2 * H * 4));
    __hip_bfloat16* gi_enc = (__hip_bfloat16*)(wsb + alloc((size_t)TIN * 65536));
    __hip_bfloat16* gi_tag = (__hip_bfloat16*)(wsb + alloc((size_t)TTAG * 65536));
    __hip_bfloat16* gi_dec = (__hip_bfloat16*)(wsb + alloc((size_t)TTGT * 65536));
    float* enc_h  = (float*)(wsb + alloc(NBATCH * H * 4));
    float* tag_h  = (float*)(wsb + alloc(NBATCH * H * 4));
    float* merged = (float*)(wsb + alloc(NBATCH * H * 4));
    float* lse    = (float*)(wsb + alloc(MT * 4));
    __hip_bfloat16* Wp_enc = (__hip_bfloat16*)(wsb + alloc(H3 * H * 2));
    __hip_bfloat16* Wp_tag = (__hip_bfloat16*)(wsb + alloc(H3 * H * 2));
    __hip_bfloat16* Wp_dec = (__hip_bfloat16*)(wsb + alloc(H3 * H * 2));
    __hip_bfloat16* outWb  = (__hip_bfloat16*)(wsb + alloc((size_t)VP * H * 2));
    __hip_bfloat16* decA   = (__hip_bfloat16*)(wsb + alloc((size_t)MT * H * 2));
    float* pmax = (float*)(wsb + alloc((size_t)MT * NT * 4));
    float* psum = (float*)(wsb + alloc((size_t)MT * NT * 4));

    float* dout = (float*)d_out;

    // 1) Wih transposes (needed by gi)
    k_prep<<<dim3(H3, 3), 256, 0, stream>>>(enc_Wih, tag_Wih, dec_Wih,
                                            W4_enc_ih, W4_tag_ih, W4_dec_ih);

    // 2) gi(enc,tag) + Whh->frags + proj transpose
    k_gi_prep<<<754, 256, 0, stream>>>(
        input_tensor, tag_tensor, enc_emb, tag_emb, W4_enc_ih, W4_tag_ih,
        enc_bih, enc_bhh, tag_bih, tag_bhh, gi_enc, gi_tag,
        enc_Whh, tag_Whh, dec_Whh, Wp_enc, Wp_tag, Wp_dec, proj_W, W4_proj);

    // 3) enc+tag scans + free-riding gi_dec + outW cvt (548 blocks)
    k_scan_enc<<<4 + TTGT + NCVT2, 1024, 0, stream>>>(
        gi_enc, Wp_enc, enc_bhh, enc_h, TIN,
        gi_tag, Wp_tag, tag_bhh, tag_h, TTAG,
        target_tensor, enc_emb, W4_dec_ih, dec_bih, dec_bhh, gi_dec,
        out_W, outWb);

    // 4) proj -> merged (tiny, 32 blocks)
    k_proj<<<NBATCH, 256, 0, stream>>>(tag_h, enc_h, W4_proj, proj_b, merged);

    // 5) dec scan (2 blocks), h0 = merged
    k_scan_dec<<<2, 1024, 0, stream>>>(gi_dec, Wp_dec, dec_bhh, decA, TTGT,
                                       merged);

    // 6) logits GEMM + LSE partials (grid = 782*20)
    k_logits<<<NT * 20, 256, 0, stream>>>(decA, outWb, out_b, dout, pmax, psum);

    // 7) per-row logsumexp
    k_lse<<<MT, 256, 0, stream>>>(pmax, psum, lse);

    // 8) loss scalars
    k_loss<<<1, 256, 0, stream>>>(lse, target_tensor, dout);
}